// Round 10
// baseline (1089.260 us; speedup 1.0000x reference)
//
#include <hip/hip_runtime.h>
#include <math.h>

// Problem constants
constexpr int DD    = 512;     // D
constexpr int D2    = 1024;    // 2D
constexpr int NTOK  = 256;     // vocab V (unique tokens = unique pipelines)
constexpr int NSYM  = 512;
constexpr int NCON  = 64;
constexpr int VOCAB = 256;
constexpr int BS_TOT = 32 * 512;   // B*S = 16384
constexpr int NDEPTH = 6;
constexpr int NLOOK  = 3;
constexpr float EPSF = 1e-8f;
constexpr float SCALE = 0.044194173824159216f; // 512^-0.5

__device__ inline void fma4(float4& a, const float4& w, float s) {
    a.x += w.x * s; a.y += w.y * s; a.z += w.z * s; a.w += w.w * s;
}

__device__ inline float wave_sum(float x) {
#pragma unroll
    for (int off = 32; off; off >>= 1) x += __shfl_xor(x, off, 64);
    return x;
}

__device__ inline void wave_argmin(float& d, int& i) {
#pragma unroll
    for (int off = 32; off; off >>= 1) {
        float od = __shfl_xor(d, off, 64);
        int   oi = __shfl_xor(i, off, 64);
        if (od < d || (od == d && oi < i)) { d = od; i = oi; }
    }
}

// ---- split-K semaphore: returns true in the LAST-arriving block of the group ----
// Producers: block-wide stores done -> syncthreads -> tid0 fence + acq_rel atomic.
// Pattern functionally proven on this chip (round-4 gsync, absmax 0.0).
__device__ inline bool sem_arrive(unsigned* c, unsigned need, int* s_flag) {
    __syncthreads();
    if (threadIdx.x == 0) {
        __threadfence();
        unsigned old = __hip_atomic_fetch_add(c, 1u, __ATOMIC_ACQ_REL, __HIP_MEMORY_SCOPE_AGENT);
        *s_flag = (old == need - 1u) ? 1 : 0;
    }
    __syncthreads();
    return *s_flag != 0;
}

__device__ inline void sem_reset(unsigned* c) {
    __syncthreads();   // tail work done by all threads before release
    if (threadIdx.x == 0)
        __hip_atomic_store(c, 0u, __ATOMIC_RELAXED, __HIP_MEMORY_SCOPE_AGENT);
}

// ================= verified GEMM body (64t x 64j, dbuf, 1 barrier/chunk) =====
// X: [256][1024] t-major. WT: [1024][N] k-major. P[slot][256][N].
__device__ __forceinline__ void d_gemmT(const float* __restrict__ WT,
                                        const float* __restrict__ X,
                                        float* __restrict__ P, int N,
                                        int j0, int t0, int k0, int NC, int slot,
                                        float* __restrict__ sX, float* __restrict__ sW) {
    constexpr int LDT = 68;
    int tid = threadIdx.x;
    int jq = tid & 15;
    int tq = tid >> 4;
    int f0 = tid * 2, f1 = tid * 2 + 1;
    int tA0 = f0 >> 3, kqA0 = f0 & 7;
    int tA1 = f1 >> 3, kqA1 = f1 & 7;
    int kwB0 = f0 >> 4, jB0 = f0 & 15;
    int kwB1 = f1 >> 4, jB1 = f1 & 15;
    float4 vx0, vx1, vw0, vw1;

#define GLOAD(kbase) do { \
        vx0 = *(const float4*)&X[(size_t)(t0 + tA0) * D2 + (kbase) + kqA0 * 4]; \
        vx1 = *(const float4*)&X[(size_t)(t0 + tA1) * D2 + (kbase) + kqA1 * 4]; \
        vw0 = *(const float4*)&WT[(size_t)((kbase) + kwB0) * N + j0 + jB0 * 4]; \
        vw1 = *(const float4*)&WT[(size_t)((kbase) + kwB1) * N + j0 + jB1 * 4]; \
    } while (0)
#define LSTORE(bufi) do { \
        float* sxB = sX + (bufi) * 2176; float* swB = sW + (bufi) * 2176; \
        sxB[(kqA0 * 4 + 0) * LDT + tA0] = vx0.x; \
        sxB[(kqA0 * 4 + 1) * LDT + tA0] = vx0.y; \
        sxB[(kqA0 * 4 + 2) * LDT + tA0] = vx0.z; \
        sxB[(kqA0 * 4 + 3) * LDT + tA0] = vx0.w; \
        sxB[(kqA1 * 4 + 0) * LDT + tA1] = vx1.x; \
        sxB[(kqA1 * 4 + 1) * LDT + tA1] = vx1.y; \
        sxB[(kqA1 * 4 + 2) * LDT + tA1] = vx1.z; \
        sxB[(kqA1 * 4 + 3) * LDT + tA1] = vx1.w; \
        *(float4*)&swB[kwB0 * LDT + jB0 * 4] = vw0; \
        *(float4*)&swB[kwB1 * LDT + jB1 * 4] = vw1; \
    } while (0)

    float4 acc0 = {0,0,0,0}, acc1 = {0,0,0,0}, acc2 = {0,0,0,0}, acc3 = {0,0,0,0};

    GLOAD(k0);
    LSTORE(0);
    __syncthreads();

    for (int kc = 0; kc < NC; ++kc) {
        if (kc + 1 < NC) GLOAD(k0 + (kc + 1) * 32);
        const float* sxB = sX + (kc & 1) * 2176;
        const float* swB = sW + (kc & 1) * 2176;
#pragma unroll 8
        for (int k = 0; k < 32; ++k) {
            float4 xa = *(const float4*)&sxB[k * LDT + tq * 4];
            float4 wb = *(const float4*)&swB[k * LDT + jq * 4];
            fma4(acc0, wb, xa.x);
            fma4(acc1, wb, xa.y);
            fma4(acc2, wb, xa.z);
            fma4(acc3, wb, xa.w);
        }
        if (kc + 1 < NC) LSTORE((kc + 1) & 1);
        __syncthreads();
    }
#undef GLOAD
#undef LSTORE

    size_t base = ((size_t)slot * NTOK + (t0 + tq * 4)) * N + j0 + jq * 4;
    *(float4*)&P[base]         = acc0;
    *(float4*)&P[base + N]     = acc1;
    *(float4*)&P[base + 2*N]   = acc2;
    *(float4*)&P[base + 3*N]   = acc3;
}

// generic GEMM launch: grid (N/64, 4, S); K-slice = KB per z-slot
template<int KB>
__global__ __launch_bounds__(256) void gemmT_kernel(const float* __restrict__ WT,
                                                    const float* __restrict__ X,
                                                    float* __restrict__ P,
                                                    int N) {
    __shared__ __align__(16) float sX[2 * 2176];
    __shared__ __align__(16) float sW[2 * 2176];
    d_gemmT(WT, X, P, N, blockIdx.x * 64, blockIdx.y * 64,
            blockIdx.z * KB, KB / 32, blockIdx.z, sX, sW);
}

// ======= cell (+optional KV) GEMM with fused split-K epilogue in last block =======
// grid 512 (cell only) or 896 (cell + KV). cnt[0..31]: cell groups (tx,jx&7), 16
// participants each. cnt[32..127]: kv tile groups, 4 participants each.
// Tail combine order identical to old epikv (ascending s), so fp-identical.
__global__ __launch_bounds__(256) void cellkvF_kernel(const float* __restrict__ CW,
                                                      const float* __restrict__ KVT,
                                                      const float* __restrict__ X,
                                                      float* __restrict__ cellP,
                                                      float* __restrict__ kvP,
                                                      float* __restrict__ z,
                                                      const float* __restrict__ kb,
                                                      const float* __restrict__ vb,
                                                      float* __restrict__ Kslot,
                                                      float* __restrict__ Vslot,
                                                      unsigned* __restrict__ cnt) {
    __shared__ __align__(16) float sX[2 * 2176];
    __shared__ __align__(16) float sW[2 * 2176];
    __shared__ int s_flag;
    int b = blockIdx.x;
    int tid = threadIdx.x;
    if (b < 512) {
        int s = b & 7, tile = b >> 3;
        int jx = tile & 15, tx = tile >> 4;
        d_gemmT(CW, X, cellP, D2, jx * 64, tx * 64, s * 128, 4, s, sX, sW);
        unsigned* c = &cnt[tx * 8 + (jx & 7)];
        if (sem_arrive(c, 16, &s_flag)) {
            int jj = (jx & 7) * 64 + (tid & 63);
            int tb = tx * 64 + (tid >> 6);
#pragma unroll 4
            for (int it = 0; it < 16; ++it) {
                int t = tb + it * 4;
                float lr = 0.f, li = 0.f;
#pragma unroll
                for (int s2 = 0; s2 < 8; ++s2) {
                    lr += cellP[((size_t)s2 * NTOK + t) * D2 + jj];
                    li += cellP[((size_t)s2 * NTOK + t) * D2 + jj + DD];
                }
                float m = sqrtf(lr * lr + li * li + EPSF);
                float inv = 1.0f / (1.0f + m);
                z[(size_t)t * D2 + jj]      = tanhf(lr * inv);
                z[(size_t)t * D2 + jj + DD] = tanhf(li * inv);
            }
            sem_reset(c);
        }
    } else {
        int q = b - 512;
        int s = q & 3, tile = q >> 2;          // tile in [0,96)
        int jx = tile % 24, tx = tile / 24;
        d_gemmT(KVT, X, kvP, 1536, jx * 64, tx * 64, s * 256, 8, s, sX, sW);
        unsigned* c = &cnt[32 + tile];
        if (sem_arrive(c, 4, &s_flag)) {
            int e = jx * 64 + (tid & 63);
            int tb = tx * 64 + (tid >> 6);
#pragma unroll 4
            for (int it = 0; it < 16; ++it) {
                int t = tb + it * 4;
                float v = 0.f;
#pragma unroll
                for (int s2 = 0; s2 < 4; ++s2)
                    v += kvP[((size_t)s2 * NTOK + t) * 1536 + e];
                if (e < DD) Kslot[(size_t)t * DD + e]        = v + kb[e];
                else        Vslot[(size_t)t * D2 + (e - DD)] = v + vb[e - DD];
            }
            sem_reset(c);
        }
    }
}

// ======= dec GEMM with fused rows-combine in last block =======
// grid (4,4,16). cnt[128..143]: tile groups, 16 participants.
__global__ __launch_bounds__(256) void decF_kernel(const float* __restrict__ decT,
                                                   const float* __restrict__ X,
                                                   float* __restrict__ decP,
                                                   const float* __restrict__ db,
                                                   float* __restrict__ rows,
                                                   unsigned* __restrict__ cnt) {
    __shared__ __align__(16) float sX[2 * 2176];
    __shared__ __align__(16) float sW[2 * 2176];
    __shared__ int s_flag;
    int jx = blockIdx.x, tx = blockIdx.y, s = blockIdx.z;
    int tid = threadIdx.x;
    d_gemmT(decT, X, decP, VOCAB, jx * 64, tx * 64, s * 64, 2, s, sX, sW);
    unsigned* c = &cnt[128 + tx * 4 + jx];
    if (sem_arrive(c, 16, &s_flag)) {
        int jj = jx * 64 + (tid & 63);
        int tb = tx * 64 + (tid >> 6);
#pragma unroll 4
        for (int it = 0; it < 16; ++it) {
            int t = tb + it * 4;
            float v = 0.f;
#pragma unroll
            for (int s2 = 0; s2 < 16; ++s2)
                v += decP[((size_t)s2 * NTOK + t) * VOCAB + jj];
            rows[(size_t)t * VOCAB + jj] = v + db[jj];
        }
        sem_reset(c);
    }
}

// ---------------- attend: wave-shuffle reduce, softmax, ctx (8 QP partials) ----------------
__global__ __launch_bounds__(256) void attend8_kernel(float* __restrict__ z,
                                                      const float* __restrict__ QP,
                                                      const float* __restrict__ qb,
                                                      const float* __restrict__ Kmem,
                                                      const float* __restrict__ Vmem,
                                                      const float* __restrict__ conf,
                                                      int M) {
    int v = blockIdx.x, tid = threadIdx.x;
    int lane = tid & 63, w = tid >> 6;
    __shared__ float s_part[4][5];
    float q0 = 0.f, q1 = 0.f;
#pragma unroll
    for (int s = 0; s < 8; ++s) {
        q0 += QP[((size_t)s * NTOK + v) * DD + tid];
        q1 += QP[((size_t)s * NTOK + v) * DD + 256 + tid];
    }
    q0 += qb[tid];
    q1 += qb[256 + tid];
    float sc[5];
#pragma unroll
    for (int m = 0; m < 5; ++m) {
        if (m < M) {
            const float* K = Kmem + (size_t)m * NTOK * DD + (size_t)v * DD;
            sc[m] = q0 * K[tid] + q1 * K[256 + tid];
        } else sc[m] = 0.f;
    }
#pragma unroll
    for (int m = 0; m < 5; ++m) {
        if (m < M) {
            float x = wave_sum(sc[m]);
            if (lane == 0) s_part[w][m] = x;
        }
    }
    __syncthreads();
    float cf = conf[v];
    float scf[5];
    float mx = -1e30f;
#pragma unroll
    for (int m = 0; m < 5; ++m) {
        if (m < M) {
            float t = (s_part[0][m] + s_part[1][m] + s_part[2][m] + s_part[3][m]) * SCALE * cf;
            scf[m] = t;
            mx = fmaxf(mx, t);
        }
    }
    float sum = 0.f;
#pragma unroll
    for (int m = 0; m < 5; ++m) {
        if (m < M) { scf[m] = expf(scf[m] - mx); sum += scf[m]; }
    }
    float inv = 1.0f / sum;
#pragma unroll
    for (int r = 0; r < 4; ++r) {
        int e = r * 256 + tid;
        float ctx = 0.f;
#pragma unroll
        for (int m = 0; m < 5; ++m)
            if (m < M) ctx += scf[m] * Vmem[(size_t)m * NTOK * D2 + (size_t)v * D2 + e];
        z[(size_t)v * D2 + e] += 0.1f * ctx * inv;
    }
}

// ---------------- finish: wave-shuffle reductions, 512 threads (8 symP partials) -----
__global__ __launch_bounds__(512) void finish8_kernel(float* __restrict__ z,
                                                      const float* __restrict__ sym,
                                                      const float* __restrict__ snorm,
                                                      const float* __restrict__ con,
                                                      const float* __restrict__ conT,
                                                      const float* __restrict__ symP,
                                                      float* __restrict__ conf,
                                                      float* __restrict__ symErr,
                                                      float* __restrict__ conErr) {
    int t0 = blockIdx.x, tid = threadIdx.x;
    int lane = tid & 63, w = tid >> 6;
    __shared__ __align__(16) float s_z[D2];
    __shared__ float wA[8];
    __shared__ float wB[8]; __shared__ int wiB[8];
    __shared__ float wC[8], wD[8];
    __shared__ float wE[8];
    __shared__ int   s_ci[1];
    __shared__ float s_pd[512], s_pc[512];

    if (tid < 256) ((float4*)s_z)[tid] = ((const float4*)(z + (size_t)t0 * D2))[tid];
    __syncthreads();
    {
        float a = s_z[tid], b = s_z[512 + tid];
        float nrm = wave_sum(a * a + b * b);
        if (lane == 0) wA[w] = nrm;
    }
    __syncthreads();
    float znorm = 0.f;
#pragma unroll
    for (int k = 0; k < 8; ++k) znorm += wA[k];
    {
        float dot = 0.f;
#pragma unroll
        for (int s = 0; s < 8; ++s)
            dot += symP[((size_t)s * NTOK + t0) * NSYM + tid];
        float d = (znorm + snorm[tid]) - 2.f * dot;
        int idx = tid;
        wave_argmin(d, idx);
        if (lane == 0) { wB[w] = d; wiB[w] = idx; }
    }
    __syncthreads();
    float dmin = wB[0]; int si = wiB[0];
#pragma unroll
    for (int k = 1; k < 8; ++k) {
        if (wB[k] < dmin || (wB[k] == dmin && wiB[k] < si)) { dmin = wB[k]; si = wiB[k]; }
    }
    if (tid == 0) conf[t0] = 1.0f / (1.0f + dmin);
    {
        const float* crow = sym + (size_t)si * D2;
        float errp = 0.f, zn2 = 0.f;
#pragma unroll
        for (int r = 0; r < 2; ++r) {
            int e = r * 512 + tid;
            float zf = s_z[e];
            float diff = crow[e] - zf;
            errp += diff * diff;
            float zn = zf + diff;
            zn2 += zn * zn;
            s_z[e] = zn;
            z[(size_t)t0 * D2 + e] = zn;
        }
        errp = wave_sum(errp);
        zn2  = wave_sum(zn2);
        if (lane == 0) { wC[w] = errp; wD[w] = zn2; }
    }
    __syncthreads();
    if (tid == 0) {
        float s = 0.f;
#pragma unroll
        for (int k = 0; k < 8; ++k) s += wC[k];
        symErr[t0] += s;
    }
    float zsnorm = 0.f;
#pragma unroll
    for (int k = 0; k < 8; ++k) zsnorm += wD[k];
    {
        int c = tid & 63, sl = tid >> 6;
        float pd = 0.f, pc = 0.f;
        int kk0 = sl * 128;
#pragma unroll 4
        for (int k = kk0; k < kk0 + 128; ++k) {
            float wv = conT[(size_t)k * NCON + c];
            pd += wv * s_z[k];
            pc += wv * wv;
        }
        s_pd[tid] = pd; s_pc[tid] = pc;
    }
    __syncthreads();
    if (tid < 64) {
        float dot2 = 0.f, cn2 = 0.f;
#pragma unroll
        for (int i = 0; i < 8; ++i) { dot2 += s_pd[tid + 64 * i]; cn2 += s_pc[tid + 64 * i]; }
        float dc = (zsnorm + cn2) - 2.f * dot2;
        int ic = tid;
        wave_argmin(dc, ic);
        if (tid == 0) s_ci[0] = ic;
    }
    __syncthreads();
    int ci0 = s_ci[0];
    {
        const float* crow = con + (size_t)ci0 * D2;
        float p = 0.f;
#pragma unroll
        for (int r = 0; r < 2; ++r) {
            int e = r * 512 + tid;
            float diff = crow[e] - s_z[e];
            p += diff * diff;
        }
        p = wave_sum(p);
        if (lane == 0) wE[w] = p;
    }
    __syncthreads();
    if (tid == 0) {
        float s = 0.f;
#pragma unroll
        for (int k = 0; k < 8; ++k) s += wE[k];
        conErr[t0] += s;
    }
}

// ---------------- scatter + in-block hist + loss (last block) ----------------
__global__ __launch_bounds__(256) void scatterloss_kernel(const int* __restrict__ x,
                                                          const float* __restrict__ rows,
                                                          float* __restrict__ out,
                                                          const float* __restrict__ symErr,
                                                          const float* __restrict__ conErr) {
    int tid = threadIdx.x;
    if (blockIdx.x == BS_TOT / 4) {
        __shared__ int h[256];
        __shared__ double rs[256], rc[256];
        h[tid] = 0;
        __syncthreads();
        for (int i = tid; i < BS_TOT; i += 256) atomicAdd(&h[x[i]], 1);
        __syncthreads();
        rs[tid] = (double)h[tid] * (double)symErr[tid];
        rc[tid] = (double)h[tid] * (double)conErr[tid];
        __syncthreads();
        for (int off = 128; off > 0; off >>= 1) {
            if (tid < off) { rs[tid] += rs[tid + off]; rc[tid] += rc[tid + off]; }
            __syncthreads();
        }
        if (tid == 0) {
            const double denom = (double)BS_TOT * (double)D2;
            out[(size_t)BS_TOT * VOCAB]     = (float)(1.25 * rs[0] / denom);
            out[(size_t)BS_TOT * VOCAB + 1] = (float)(1.25 * rc[0] / denom);
        }
        return;
    }
    int pos = blockIdx.x * 4 + (tid >> 6);
    int lane = tid & 63;
    int v = x[pos];
    const float4* r = (const float4*)(rows + (size_t)v * VOCAB);
    ((float4*)(out + (size_t)pos * VOCAB))[lane] = r[lane];
}

// ---------------- fused setup: transposes + zero + buildcw + embed + symnorm + cnt ------
// grid 3905, block 512 flat.
__global__ __launch_bounds__(512) void setup_kernel(const float* __restrict__ qw,
                                                    const float* __restrict__ kw,
                                                    const float* __restrict__ vw,
                                                    const float* __restrict__ sym,
                                                    const float* __restrict__ dec_w,
                                                    const float* __restrict__ con,
                                                    const float* __restrict__ Wr,
                                                    const float* __restrict__ Wi,
                                                    const float* __restrict__ mag,
                                                    const float* __restrict__ phase,
                                                    float* __restrict__ qwT,
                                                    float* __restrict__ KVT,
                                                    float* __restrict__ symT,
                                                    float* __restrict__ decT,
                                                    float* __restrict__ conT,
                                                    float* __restrict__ CW,
                                                    float* __restrict__ dst,
                                                    float* __restrict__ snorm,
                                                    float* __restrict__ symErr,
                                                    float* __restrict__ conErr,
                                                    unsigned* __restrict__ cnt) {
    __shared__ float t[32][33];
    __shared__ float tr[32][33], ti[32][33];
    __shared__ float s_w[8];
    int b = blockIdx.x;
    int tid = threadIdx.x;

    if (b < 2880) {   // transposes (all sources have 1024 columns)
        const float* in; float* outp; int ldo;
        if      (b < 512)  {           in = qw;    outp = qwT;      ldo = DD;    }
        else if (b < 1024) { b -= 512; in = kw;    outp = KVT;      ldo = 1536;  }
        else if (b < 2048) { b -= 1024; in = vw;   outp = KVT + DD; ldo = 1536;  }
        else if (b < 2560) { b -= 2048; in = sym;  outp = symT;     ldo = NSYM;  }
        else if (b < 2816) { b -= 2560; in = dec_w; outp = decT;    ldo = VOCAB; }
        else               { b -= 2816; in = con;  outp = conT;     ldo = NCON;  }
        int bx = b & 31, by = b >> 5;
        int c0 = bx * 32, r0 = by * 32;
        int xx = tid & 31, yy = tid >> 5;   // yy in 0..15
#pragma unroll
        for (int i = 0; i < 32; i += 16)
            t[yy + i][xx] = in[(size_t)(r0 + yy + i) * D2 + c0 + xx];
        __syncthreads();
#pragma unroll
        for (int i = 0; i < 32; i += 16)
            outp[(size_t)(c0 + yy + i) * ldo + r0 + xx] = t[xx][yy + i];
        return;
    }
    if (b == 2880) {
        if (tid < 256) { symErr[tid] = 0.f; conErr[tid] = 0.f; }
        if (tid < 144) cnt[tid] = 0u;
        return;
    }
    if (b < 3137) {   // buildcw, 256 blocks
        int q = b - 2881;
        int j0 = (q & 15) * 32, k0 = (q >> 4) * 32;
        int xx = tid & 31, yy = tid >> 5;
#pragma unroll
        for (int i = 0; i < 32; i += 16) {
            tr[yy + i][xx] = Wr[(size_t)(j0 + yy + i) * DD + k0 + xx];
            ti[yy + i][xx] = Wi[(size_t)(j0 + yy + i) * DD + k0 + xx];
        }
        __syncthreads();
#pragma unroll
        for (int i = 0; i < 32; i += 16) {
            float vr = tr[xx][yy + i];
            float vi = ti[xx][yy + i];
            int k = k0 + yy + i, j = j0 + xx;
            CW[(size_t)k * D2 + j]             = vr;
            CW[(size_t)k * D2 + DD + j]        = vi;
            CW[(size_t)(DD + k) * D2 + j]      = -vi;
            CW[(size_t)(DD + k) * D2 + DD + j] = vr;
        }
        return;
    }
    if (b < 3393) {   // embed, 256 blocks, 512 threads = 512 j
        int v = b - 3137, j = tid;
        float r = mag[v * DD + j], th = phase[v * DD + j];
        dst[(size_t)v * D2 + j]      = r * cosf(th);
        dst[(size_t)v * D2 + DD + j] = r * sinf(th);
        return;
    }
    {   // symnorm, 512 blocks
        int c = b - 3393;
        float2 vv = ((const float2*)(sym + (size_t)c * D2))[tid];
        float p = vv.x * vv.x + vv.y * vv.y;
        p = wave_sum(p);
        int lane = tid & 63, w = tid >> 6;
        if (lane == 0) s_w[w] = p;
        __syncthreads();
        if (tid == 0) {
            float s = 0.f;
#pragma unroll
            for (int k = 0; k < 8; ++k) s += s_w[k];
            snorm[c] = s;
        }
    }
}

// ---------------- host ----------------
extern "C" void kernel_launch(void* const* d_in, const int* in_sizes, int n_in,
                              void* d_out, int out_size, void* d_ws, size_t ws_size,
                              hipStream_t stream) {
    const int*   x     = (const int*)  d_in[0];
    const float* mag   = (const float*)d_in[1];
    const float* phase = (const float*)d_in[2];
    const float* Wr    = (const float*)d_in[3];
    const float* Wi    = (const float*)d_in[4];
    const float* qw    = (const float*)d_in[5];
    const float* qb    = (const float*)d_in[6];
    const float* kw    = (const float*)d_in[7];
    const float* kb    = (const float*)d_in[8];
    const float* vw    = (const float*)d_in[9];
    const float* vb    = (const float*)d_in[10];
    const float* dec_w = (const float*)d_in[11];
    const float* dec_b = (const float*)d_in[12];
    const float* sym   = (const float*)d_in[13];
    const float* con   = (const float*)d_in[14];
    float* out = (float*)d_out;

    // workspace layout (floats); total ~42.5 MB
    float* ws     = (float*)d_ws;
    float* bufA   = ws;                          // 262144
    float* bufB   = bufA + NTOK * D2;            // 262144
    float* Kmem   = bufB + NTOK * D2;            // 786432
    float* Vmem   = Kmem + NDEPTH * NTOK * DD;   // 1572864
    float* rows   = Vmem + NDEPTH * NTOK * D2;   // 65536
    float* CW     = rows + NTOK * VOCAB;         // 1048576
    float* qwT    = CW + D2 * D2;                // 524288
    float* KVT    = qwT + D2 * DD;               // 1572864
    float* symT   = KVT + D2 * 1536;             // 524288
    float* decT   = symT + D2 * NSYM;            // 262144
    float* conT   = decT + D2 * VOCAB;           // 65536
    float* bigP   = conT + D2 * NCON;            // 2097152
    float* kvP    = bigP + 8 * NTOK * D2;        // 1572864
    float* snorm  = kvP + 4 * NTOK * 1536;       // 512
    float* conf   = snorm + NSYM;                // 256
    float* symErr = conf + NTOK;                 // 256
    float* conErr = symErr + NTOK;               // 256
    unsigned* cnt = (unsigned*)(conErr + NTOK);  // 144 (rounded to 256)

    float* QP   = bigP;                 // 8*256*512
    float* symP = bigP + 1048576;       // 8*256*512
    float* decP = bigP;                 // 16*256*256

    setup_kernel<<<3905, 512, 0, stream>>>(qw, kw, vw, sym, dec_w, con, Wr, Wi, mag, phase,
                                           qwT, KVT, symT, decT, conT, CW,
                                           bufA, snorm, symErr, conErr, cnt);

    float* cur = bufA;
    float* oth = bufB;
    for (int d = 0; d < NDEPTH; ++d) {
        if (d == 0) {
            cellkvF_kernel<<<512, 256, 0, stream>>>(CW, KVT, cur, bigP, kvP, oth,
                                                    kb, vb, Kmem, Vmem, cnt);
        } else {
            // cell(d) + KV(slot d-1) share the same input `cur`; tails write z + KV slot
            cellkvF_kernel<<<896, 256, 0, stream>>>(CW, KVT, cur, bigP, kvP, oth,
                                                    kb, vb,
                                                    Kmem + (size_t)(d - 1) * NTOK * DD,
                                                    Vmem + (size_t)(d - 1) * NTOK * D2,
                                                    cnt);
        }
        { float* t = cur; cur = oth; oth = t; }
        if (d > 0) {
            gemmT_kernel<128><<<dim3(8, 4, 8), 256, 0, stream>>>(qwT, cur, QP, DD);
            attend8_kernel<<<NTOK, 256, 0, stream>>>(cur, QP, qb, Kmem, Vmem, conf, d);
        }
        gemmT_kernel<128><<<dim3(8, 4, 8), 256, 0, stream>>>(symT, cur, symP, NSYM);
        finish8_kernel<<<NTOK, 512, 0, stream>>>(cur, sym, snorm, con, conT, symP,
                                                 conf, symErr, conErr);
    }
    for (int l = 0; l < NLOOK; ++l) {
        cellkvF_kernel<<<512, 256, 0, stream>>>(CW, KVT, cur, bigP, kvP, oth,
                                                kb, vb, Kmem, Vmem, cnt);
        { float* t = cur; cur = oth; oth = t; }
    }
    decF_kernel<<<dim3(4, 4, 16), 256, 0, stream>>>(decT, cur, decP, dec_b, rows, cnt);
    scatterloss_kernel<<<BS_TOT / 4 + 1, 256, 0, stream>>>(x, rows, out, symErr, conErr);
}

// Round 12
// 447.240 us; speedup vs baseline: 2.4355x; 2.4355x over previous
//
#include <hip/hip_runtime.h>
#include <math.h>

// Problem constants
constexpr int DD    = 512;     // D
constexpr int D2    = 1024;    // 2D
constexpr int NTOK  = 256;     // vocab V (unique tokens = unique pipelines)
constexpr int NSYM  = 512;
constexpr int NCON  = 64;
constexpr int VOCAB = 256;
constexpr int BS_TOT = 32 * 512;   // B*S = 16384
constexpr int NDEPTH = 6;
constexpr int NLOOK  = 3;
constexpr float EPSF = 1e-8f;
constexpr float SCALE = 0.044194173824159216f; // 512^-0.5

__device__ inline void fma4(float4& a, const float4& w, float s) {
    a.x += w.x * s; a.y += w.y * s; a.z += w.z * s; a.w += w.w * s;
}

__device__ inline float wave_sum(float x) {
#pragma unroll
    for (int off = 32; off; off >>= 1) x += __shfl_xor(x, off, 64);
    return x;
}

__device__ inline void wave_argmin(float& d, int& i) {
#pragma unroll
    for (int off = 32; off; off >>= 1) {
        float od = __shfl_xor(d, off, 64);
        int   oi = __shfl_xor(i, off, 64);
        if (od < d || (od == d && oi < i)) { d = od; i = oi; }
    }
}

// ================= verified GEMM body (64t x 64j, dbuf, 1 barrier/chunk) =====
// X: [M][1024] t-major. WT: [1024][N] k-major. P[slot][mstr][N].
__device__ __forceinline__ void d_gemmT(const float* __restrict__ WT,
                                        const float* __restrict__ X,
                                        float* __restrict__ P, int N,
                                        int j0, int t0, int k0, int NC, int slot,
                                        int mstr,
                                        float* __restrict__ sX, float* __restrict__ sW) {
    constexpr int LDT = 68;
    int tid = threadIdx.x;
    int jq = tid & 15;
    int tq = tid >> 4;
    int f0 = tid * 2, f1 = tid * 2 + 1;
    int tA0 = f0 >> 3, kqA0 = f0 & 7;
    int tA1 = f1 >> 3, kqA1 = f1 & 7;
    int kwB0 = f0 >> 4, jB0 = f0 & 15;
    int kwB1 = f1 >> 4, jB1 = f1 & 15;
    float4 vx0, vx1, vw0, vw1;

#define GLOAD(kbase) do { \
        vx0 = *(const float4*)&X[(size_t)(t0 + tA0) * D2 + (kbase) + kqA0 * 4]; \
        vx1 = *(const float4*)&X[(size_t)(t0 + tA1) * D2 + (kbase) + kqA1 * 4]; \
        vw0 = *(const float4*)&WT[(size_t)((kbase) + kwB0) * N + j0 + jB0 * 4]; \
        vw1 = *(const float4*)&WT[(size_t)((kbase) + kwB1) * N + j0 + jB1 * 4]; \
    } while (0)
#define LSTORE(bufi) do { \
        float* sxB = sX + (bufi) * 2176; float* swB = sW + (bufi) * 2176; \
        sxB[(kqA0 * 4 + 0) * LDT + tA0] = vx0.x; \
        sxB[(kqA0 * 4 + 1) * LDT + tA0] = vx0.y; \
        sxB[(kqA0 * 4 + 2) * LDT + tA0] = vx0.z; \
        sxB[(kqA0 * 4 + 3) * LDT + tA0] = vx0.w; \
        sxB[(kqA1 * 4 + 0) * LDT + tA1] = vx1.x; \
        sxB[(kqA1 * 4 + 1) * LDT + tA1] = vx1.y; \
        sxB[(kqA1 * 4 + 2) * LDT + tA1] = vx1.z; \
        sxB[(kqA1 * 4 + 3) * LDT + tA1] = vx1.w; \
        *(float4*)&swB[kwB0 * LDT + jB0 * 4] = vw0; \
        *(float4*)&swB[kwB1 * LDT + jB1 * 4] = vw1; \
    } while (0)

    float4 acc0 = {0,0,0,0}, acc1 = {0,0,0,0}, acc2 = {0,0,0,0}, acc3 = {0,0,0,0};

    GLOAD(k0);
    LSTORE(0);
    __syncthreads();

    for (int kc = 0; kc < NC; ++kc) {
        if (kc + 1 < NC) GLOAD(k0 + (kc + 1) * 32);
        const float* sxB = sX + (kc & 1) * 2176;
        const float* swB = sW + (kc & 1) * 2176;
#pragma unroll 8
        for (int k = 0; k < 32; ++k) {
            float4 xa = *(const float4*)&sxB[k * LDT + tq * 4];
            float4 wb = *(const float4*)&swB[k * LDT + jq * 4];
            fma4(acc0, wb, xa.x);
            fma4(acc1, wb, xa.y);
            fma4(acc2, wb, xa.z);
            fma4(acc3, wb, xa.w);
        }
        if (kc + 1 < NC) LSTORE((kc + 1) & 1);
        __syncthreads();
    }
#undef GLOAD
#undef LSTORE

    size_t base = ((size_t)slot * mstr + (t0 + tq * 4)) * N + j0 + jq * 4;
    *(float4*)&P[base]         = acc0;
    *(float4*)&P[base + N]     = acc1;
    *(float4*)&P[base + 2*N]   = acc2;
    *(float4*)&P[base + 3*N]   = acc3;
}

// generic GEMM launch: grid (N/64, 4, S); K-slice = KB per z-slot
template<int KB>
__global__ __launch_bounds__(256) void gemmT_kernel(const float* __restrict__ WT,
                                                    const float* __restrict__ X,
                                                    float* __restrict__ P,
                                                    int N) {
    __shared__ __align__(16) float sX[2 * 2176];
    __shared__ __align__(16) float sW[2 * 2176];
    d_gemmT(WT, X, P, N, blockIdx.x * 64, blockIdx.y * 64,
            blockIdx.z * KB, KB / 32, blockIdx.z, NTOK, sX, sW);
}

// ---- precompute SC = sym @ CW (512x1024) and SKV = sym @ KVT (512x1536), full-K ----
// grid 320 flat: blocks [0,128) SC (16j x 8t), [128,320) SKV (24j x 8t). NC=32.
__global__ __launch_bounds__(256) void precomp_kernel(const float* __restrict__ CW,
                                                      const float* __restrict__ KVT,
                                                      const float* __restrict__ sym,
                                                      float* __restrict__ SC,
                                                      float* __restrict__ SKV) {
    __shared__ __align__(16) float sX[2 * 2176];
    __shared__ __align__(16) float sW[2 * 2176];
    int b = blockIdx.x;
    if (b < 128) {
        int jx = b & 15, tx = b >> 4;
        d_gemmT(CW, sym, SC, 1024, jx * 64, tx * 64, 0, 32, 0, NSYM, sX, sW);
    } else {
        int q = b - 128;
        int jx = q % 24, tx = q / 24;
        d_gemmT(KVT, sym, SKV, 1536, jx * 64, tx * 64, 0, 32, 0, NSYM, sX, sW);
    }
}

// ---------------- cell epilogue: combine 8 partials + tanh-norm. grid (2,256) --------
__global__ __launch_bounds__(256) void epi_kernel(const float* __restrict__ cellP,
                                                  float* __restrict__ z) {
    int bx = blockIdx.x, t = blockIdx.y, tid = threadIdx.x;
    int j = bx * 256 + tid;
    float lr = 0.f, li = 0.f;
#pragma unroll
    for (int s = 0; s < 8; ++s) {
        lr += cellP[((size_t)s * NTOK + t) * D2 + j];
        li += cellP[((size_t)s * NTOK + t) * D2 + DD + j];
    }
    float m = sqrtf(lr * lr + li * li + EPSF);
    float inv = 1.0f / (1.0f + m);
    z[(size_t)t * D2 + j]      = tanhf(lr * inv);
    z[(size_t)t * D2 + DD + j] = tanhf(li * inv);
}

// ---------------- attend: wave-shuffle reduce, softmax, ctx (8 QP partials) ----------------
__global__ __launch_bounds__(256) void attend8_kernel(float* __restrict__ z,
                                                      const float* __restrict__ QP,
                                                      const float* __restrict__ qb,
                                                      const float* __restrict__ Kmem,
                                                      const float* __restrict__ Vmem,
                                                      const float* __restrict__ conf,
                                                      int M) {
    int v = blockIdx.x, tid = threadIdx.x;
    int lane = tid & 63, w = tid >> 6;
    __shared__ float s_part[4][5];
    float q0 = 0.f, q1 = 0.f;
#pragma unroll
    for (int s = 0; s < 8; ++s) {
        q0 += QP[((size_t)s * NTOK + v) * DD + tid];
        q1 += QP[((size_t)s * NTOK + v) * DD + 256 + tid];
    }
    q0 += qb[tid];
    q1 += qb[256 + tid];
    float sc[5];
#pragma unroll
    for (int m = 0; m < 5; ++m) {
        if (m < M) {
            const float* K = Kmem + (size_t)m * NTOK * DD + (size_t)v * DD;
            sc[m] = q0 * K[tid] + q1 * K[256 + tid];
        } else sc[m] = 0.f;
    }
#pragma unroll
    for (int m = 0; m < 5; ++m) {
        if (m < M) {
            float x = wave_sum(sc[m]);
            if (lane == 0) s_part[w][m] = x;
        }
    }
    __syncthreads();
    float cf = conf[v];
    float scf[5];
    float mx = -1e30f;
#pragma unroll
    for (int m = 0; m < 5; ++m) {
        if (m < M) {
            float t = (s_part[0][m] + s_part[1][m] + s_part[2][m] + s_part[3][m]) * SCALE * cf;
            scf[m] = t;
            mx = fmaxf(mx, t);
        }
    }
    float sum = 0.f;
#pragma unroll
    for (int m = 0; m < 5; ++m) {
        if (m < M) { scf[m] = expf(scf[m] - mx); sum += scf[m]; }
    }
    float inv = 1.0f / sum;
#pragma unroll
    for (int r = 0; r < 4; ++r) {
        int e = r * 256 + tid;
        float ctx = 0.f;
#pragma unroll
        for (int m = 0; m < 5; ++m)
            if (m < M) ctx += scf[m] * Vmem[(size_t)m * NTOK * D2 + (size_t)v * D2 + e];
        z[(size_t)v * D2 + e] += 0.1f * ctx * inv;
    }
}

// ------- finishG: round-9 finish + fused next-cell gather (SC) + KV gather (SKV) -------
// After si is known: z_mid[t] = tanh-norm(SC[si]) (= next cell / look1 output),
// K/V slot = SKV[si] + bias. zs itself is never materialized (forward value = sym[si]).
__global__ __launch_bounds__(512) void finishG_kernel(const float* __restrict__ z,
                                                      const float* __restrict__ sym,
                                                      const float* __restrict__ snorm,
                                                      const float* __restrict__ con,
                                                      const float* __restrict__ conT,
                                                      const float* __restrict__ symP,
                                                      float* __restrict__ conf,
                                                      float* __restrict__ symErr,
                                                      float* __restrict__ conErr,
                                                      const float* __restrict__ SC,
                                                      const float* __restrict__ SKV,
                                                      float* __restrict__ zmid,
                                                      const float* __restrict__ kb,
                                                      const float* __restrict__ vb,
                                                      float* __restrict__ Kslot,
                                                      float* __restrict__ Vslot,
                                                      int doKV) {
    int t0 = blockIdx.x, tid = threadIdx.x;
    int lane = tid & 63, w = tid >> 6;
    __shared__ __align__(16) float s_z[D2];
    __shared__ float wA[8];
    __shared__ float wB[8]; __shared__ int wiB[8];
    __shared__ float wC[8], wD[8];
    __shared__ float wE[8];
    __shared__ int   s_ci[1];
    __shared__ float s_pd[512], s_pc[512];

    if (tid < 256) ((float4*)s_z)[tid] = ((const float4*)(z + (size_t)t0 * D2))[tid];
    __syncthreads();
    {
        float a = s_z[tid], b = s_z[512 + tid];
        float nrm = wave_sum(a * a + b * b);
        if (lane == 0) wA[w] = nrm;
    }
    __syncthreads();
    float znorm = 0.f;
#pragma unroll
    for (int k = 0; k < 8; ++k) znorm += wA[k];
    {
        float dot = 0.f;
#pragma unroll
        for (int s = 0; s < 8; ++s)
            dot += symP[((size_t)s * NTOK + t0) * NSYM + tid];
        float d = (znorm + snorm[tid]) - 2.f * dot;
        int idx = tid;
        wave_argmin(d, idx);
        if (lane == 0) { wB[w] = d; wiB[w] = idx; }
    }
    __syncthreads();
    float dmin = wB[0]; int si = wiB[0];
#pragma unroll
    for (int k = 1; k < 8; ++k) {
        if (wB[k] < dmin || (wB[k] == dmin && wiB[k] < si)) { dmin = wB[k]; si = wiB[k]; }
    }
    if (tid == 0) conf[t0] = 1.0f / (1.0f + dmin);
    // straight-through (in s_z only; zs never stored) + symErr + ||zs||^2
    {
        const float* crow = sym + (size_t)si * D2;
        float errp = 0.f, zn2 = 0.f;
#pragma unroll
        for (int r = 0; r < 2; ++r) {
            int e = r * 512 + tid;
            float zf = s_z[e];
            float diff = crow[e] - zf;
            errp += diff * diff;
            float zn = zf + diff;
            zn2 += zn * zn;
            s_z[e] = zn;
        }
        errp = wave_sum(errp);
        zn2  = wave_sum(zn2);
        if (lane == 0) { wC[w] = errp; wD[w] = zn2; }
    }
    __syncthreads();
    if (tid == 0) {
        float s = 0.f;
#pragma unroll
        for (int k = 0; k < 8; ++k) s += wC[k];
        symErr[t0] += s;
    }
    float zsnorm = 0.f;
#pragma unroll
    for (int k = 0; k < 8; ++k) zsnorm += wD[k];
    {
        int c = tid & 63, sl = tid >> 6;
        float pd = 0.f, pc = 0.f;
        int kk0 = sl * 128;
#pragma unroll 4
        for (int k = kk0; k < kk0 + 128; ++k) {
            float wv = conT[(size_t)k * NCON + c];
            pd += wv * s_z[k];
            pc += wv * wv;
        }
        s_pd[tid] = pd; s_pc[tid] = pc;
    }
    __syncthreads();
    if (tid < 64) {
        float dot2 = 0.f, cn2 = 0.f;
#pragma unroll
        for (int i = 0; i < 8; ++i) { dot2 += s_pd[tid + 64 * i]; cn2 += s_pc[tid + 64 * i]; }
        float dc = (zsnorm + cn2) - 2.f * dot2;
        int ic = tid;
        wave_argmin(dc, ic);
        if (tid == 0) s_ci[0] = ic;
    }
    __syncthreads();
    int ci0 = s_ci[0];
    {
        const float* crow = con + (size_t)ci0 * D2;
        float p = 0.f;
#pragma unroll
        for (int r = 0; r < 2; ++r) {
            int e = r * 512 + tid;
            float diff = crow[e] - s_z[e];
            p += diff * diff;
        }
        p = wave_sum(p);
        if (lane == 0) wE[w] = p;
    }
    __syncthreads();
    if (tid == 0) {
        float s = 0.f;
#pragma unroll
        for (int k = 0; k < 8; ++k) s += wE[k];
        conErr[t0] += s;
    }

    // ---- fused tail: next-cell gather + tanh-norm, and KV slot gather + bias ----
    {
        const float* scr = SC + (size_t)si * D2;
        int j = tid;                       // 0..511
        float lr = scr[j], li = scr[j + DD];
        float m = sqrtf(lr * lr + li * li + EPSF);
        float inv = 1.0f / (1.0f + m);
        zmid[(size_t)t0 * D2 + j]      = tanhf(lr * inv);
        zmid[(size_t)t0 * D2 + DD + j] = tanhf(li * inv);
        if (doKV) {
            const float* skr = SKV + (size_t)si * 1536;
#pragma unroll
            for (int it = 0; it < 3; ++it) {
                int e = it * 512 + tid;
                float v = skr[e];
                if (e < DD) Kslot[(size_t)t0 * DD + e]        = v + kb[e];
                else        Vslot[(size_t)t0 * D2 + (e - DD)] = v + vb[e - DD];
            }
        }
    }
}

// ---------------- dec combine: rows = sum of 16 partials + dec_b ----------------
__global__ void deccomb_kernel(const float* __restrict__ P, const float* __restrict__ db,
                               float* __restrict__ rows) {
    int t = blockIdx.x, j = threadIdx.x;
    float v = 0.f;
#pragma unroll
    for (int s = 0; s < 16; ++s)
        v += P[((size_t)s * NTOK + t) * VOCAB + j];
    rows[(size_t)t * VOCAB + j] = v + db[j];
}

// ---------------- scatter + in-block hist + loss (last block) ----------------
__global__ __launch_bounds__(256) void scatterloss_kernel(const int* __restrict__ x,
                                                          const float* __restrict__ rows,
                                                          float* __restrict__ out,
                                                          const float* __restrict__ symErr,
                                                          const float* __restrict__ conErr) {
    int tid = threadIdx.x;
    if (blockIdx.x == BS_TOT / 4) {
        __shared__ int h[256];
        __shared__ double rs[256], rc[256];
        h[tid] = 0;
        __syncthreads();
        for (int i = tid; i < BS_TOT; i += 256) atomicAdd(&h[x[i]], 1);
        __syncthreads();
        rs[tid] = (double)h[tid] * (double)symErr[tid];
        rc[tid] = (double)h[tid] * (double)conErr[tid];
        __syncthreads();
        for (int off = 128; off > 0; off >>= 1) {
            if (tid < off) { rs[tid] += rs[tid + off]; rc[tid] += rc[tid + off]; }
            __syncthreads();
        }
        if (tid == 0) {
            const double denom = (double)BS_TOT * (double)D2;
            out[(size_t)BS_TOT * VOCAB]     = (float)(1.25 * rs[0] / denom);
            out[(size_t)BS_TOT * VOCAB + 1] = (float)(1.25 * rc[0] / denom);
        }
        return;
    }
    int pos = blockIdx.x * 4 + (tid >> 6);
    int lane = tid & 63;
    int v = x[pos];
    const float4* r = (const float4*)(rows + (size_t)v * VOCAB);
    ((float4*)(out + (size_t)pos * VOCAB))[lane] = r[lane];
}

// ---------------- fused setup: 6 transposes + zero + buildcw + embed + symnorm ----------
// grid 3905, block 512 flat.
__global__ __launch_bounds__(512) void setup_kernel(const float* __restrict__ qw,
                                                    const float* __restrict__ kw,
                                                    const float* __restrict__ vw,
                                                    const float* __restrict__ sym,
                                                    const float* __restrict__ dec_w,
                                                    const float* __restrict__ con,
                                                    const float* __restrict__ Wr,
                                                    const float* __restrict__ Wi,
                                                    const float* __restrict__ mag,
                                                    const float* __restrict__ phase,
                                                    float* __restrict__ qwT,
                                                    float* __restrict__ KVT,
                                                    float* __restrict__ symT,
                                                    float* __restrict__ decT,
                                                    float* __restrict__ conT,
                                                    float* __restrict__ CW,
                                                    float* __restrict__ dst,
                                                    float* __restrict__ snorm,
                                                    float* __restrict__ symErr,
                                                    float* __restrict__ conErr) {
    __shared__ float t[32][33];
    __shared__ float tr[32][33], ti[32][33];
    __shared__ float s_w[8];
    int b = blockIdx.x;
    int tid = threadIdx.x;

    if (b < 2880) {   // transposes (all sources have 1024 columns)
        const float* in; float* outp; int ldo;
        if      (b < 512)  {           in = qw;    outp = qwT;      ldo = DD;    }
        else if (b < 1024) { b -= 512; in = kw;    outp = KVT;      ldo = 1536;  }
        else if (b < 2048) { b -= 1024; in = vw;   outp = KVT + DD; ldo = 1536;  }
        else if (b < 2560) { b -= 2048; in = sym;  outp = symT;     ldo = NSYM;  }
        else if (b < 2816) { b -= 2560; in = dec_w; outp = decT;    ldo = VOCAB; }
        else               { b -= 2816; in = con;  outp = conT;     ldo = NCON;  }
        int bx = b & 31, by = b >> 5;
        int c0 = bx * 32, r0 = by * 32;
        int xx = tid & 31, yy = tid >> 5;   // yy in 0..15
#pragma unroll
        for (int i = 0; i < 32; i += 16)
            t[yy + i][xx] = in[(size_t)(r0 + yy + i) * D2 + c0 + xx];
        __syncthreads();
#pragma unroll
        for (int i = 0; i < 32; i += 16)
            outp[(size_t)(c0 + yy + i) * ldo + r0 + xx] = t[xx][yy + i];
        return;
    }
    if (b == 2880) {
        if (tid < 256) { symErr[tid] = 0.f; conErr[tid] = 0.f; }
        return;
    }
    if (b < 3137) {   // buildcw, 256 blocks
        int q = b - 2881;
        int j0 = (q & 15) * 32, k0 = (q >> 4) * 32;
        int xx = tid & 31, yy = tid >> 5;
#pragma unroll
        for (int i = 0; i < 32; i += 16) {
            tr[yy + i][xx] = Wr[(size_t)(j0 + yy + i) * DD + k0 + xx];
            ti[yy + i][xx] = Wi[(size_t)(j0 + yy + i) * DD + k0 + xx];
        }
        __syncthreads();
#pragma unroll
        for (int i = 0; i < 32; i += 16) {
            float vr = tr[xx][yy + i];
            float vi = ti[xx][yy + i];
            int k = k0 + yy + i, j = j0 + xx;
            CW[(size_t)k * D2 + j]             = vr;
            CW[(size_t)k * D2 + DD + j]        = vi;
            CW[(size_t)(DD + k) * D2 + j]      = -vi;
            CW[(size_t)(DD + k) * D2 + DD + j] = vr;
        }
        return;
    }
    if (b < 3393) {   // embed, 256 blocks, 512 threads = 512 j
        int v = b - 3137, j = tid;
        float r = mag[v * DD + j], th = phase[v * DD + j];
        dst[(size_t)v * D2 + j]      = r * cosf(th);
        dst[(size_t)v * D2 + DD + j] = r * sinf(th);
        return;
    }
    {   // symnorm, 512 blocks
        int c = b - 3393;
        float2 vv = ((const float2*)(sym + (size_t)c * D2))[tid];
        float p = vv.x * vv.x + vv.y * vv.y;
        p = wave_sum(p);
        int lane = tid & 63, w = tid >> 6;
        if (lane == 0) s_w[w] = p;
        __syncthreads();
        if (tid == 0) {
            float s = 0.f;
#pragma unroll
            for (int k = 0; k < 8; ++k) s += s_w[k];
            snorm[c] = s;
        }
    }
}

// ---------------- host ----------------
extern "C" void kernel_launch(void* const* d_in, const int* in_sizes, int n_in,
                              void* d_out, int out_size, void* d_ws, size_t ws_size,
                              hipStream_t stream) {
    const int*   x     = (const int*)  d_in[0];
    const float* mag   = (const float*)d_in[1];
    const float* phase = (const float*)d_in[2];
    const float* Wr    = (const float*)d_in[3];
    const float* Wi    = (const float*)d_in[4];
    const float* qw    = (const float*)d_in[5];
    const float* qb    = (const float*)d_in[6];
    const float* kw    = (const float*)d_in[7];
    const float* kb    = (const float*)d_in[8];
    const float* vw    = (const float*)d_in[9];
    const float* vb    = (const float*)d_in[10];
    const float* dec_w = (const float*)d_in[11];
    const float* dec_b = (const float*)d_in[12];
    const float* sym   = (const float*)d_in[13];
    const float* con   = (const float*)d_in[14];
    float* out = (float*)d_out;

    // workspace layout (floats); total ~42.5 MB (SC/SKV reuse old kvP region)
    float* ws     = (float*)d_ws;
    float* bufA   = ws;                          // 262144
    float* bufB   = bufA + NTOK * D2;            // 262144
    float* Kmem   = bufB + NTOK * D2;            // 786432
    float* Vmem   = Kmem + NDEPTH * NTOK * DD;   // 1572864
    float* rows   = Vmem + NDEPTH * NTOK * D2;   // 65536
    float* CW     = rows + NTOK * VOCAB;         // 1048576
    float* qwT    = CW + D2 * D2;                // 524288
    float* KVT    = qwT + D2 * DD;               // 1572864
    float* symT   = KVT + D2 * 1536;             // 524288
    float* decT   = symT + D2 * NSYM;            // 262144
    float* conT   = decT + D2 * VOCAB;           // 65536
    float* bigP   = conT + D2 * NCON;            // 2097152
    float* SC     = bigP + 8 * NTOK * D2;        // 524288  (old kvP region)
    float* SKV    = SC + NSYM * D2;              // 786432  (fits in old kvP 1572864)
    float* snorm  = bigP + 8 * NTOK * D2 + 4 * NTOK * 1536;  // 512 (unchanged offset)
    float* conf   = snorm + NSYM;                // 256
    float* symErr = conf + NTOK;                 // 256
    float* conErr = symErr + NTOK;               // 256

    float* QP   = bigP;                 // 8*256*512
    float* symP = bigP + 1048576;       // 8*256*512
    float* decP = bigP;                 // 16*256*256

    setup_kernel<<<3905, 512, 0, stream>>>(qw, kw, vw, sym, dec_w, con, Wr, Wi, mag, phase,
                                           qwT, KVT, symT, decT, conT, CW,
                                           bufA, snorm, symErr, conErr);
    precomp_kernel<<<320, 256, 0, stream>>>(CW, KVT, sym, SC, SKV);

    // ---------- d = 0: real cell GEMM (embed input), then sym + finishG ----------
    gemmT_kernel<128><<<dim3(16, 4, 8), 256, 0, stream>>>(CW, bufA, bigP, D2);
    epi_kernel<<<dim3(2, 256), 256, 0, stream>>>(bigP, bufB);
    gemmT_kernel<128><<<dim3(8, 4, 8), 256, 0, stream>>>(symT, bufB, symP, NSYM);
    finishG_kernel<<<NTOK, 512, 0, stream>>>(bufB, sym, snorm, con, conT, symP,
                                             conf, symErr, conErr,
                                             SC, SKV, bufA, kb, vb,
                                             Kmem, Vmem, 1);
    float* cur = bufA;   // z_mid for depth 1
    float* oth = bufB;

    // ---------- d = 1..5: qgemm -> attend -> symgemm -> finishG (cell+KV fused) ------
    for (int d = 1; d < NDEPTH; ++d) {
        gemmT_kernel<128><<<dim3(8, 4, 8), 256, 0, stream>>>(qwT, cur, QP, DD);
        attend8_kernel<<<NTOK, 256, 0, stream>>>(cur, QP, qb, Kmem, Vmem, conf, d);
        gemmT_kernel<128><<<dim3(8, 4, 8), 256, 0, stream>>>(symT, cur, symP, NSYM);
        finishG_kernel<<<NTOK, 512, 0, stream>>>(cur, sym, snorm, con, conT, symP,
                                                 conf, symErr, conErr,
                                                 SC, SKV, oth, kb, vb,
                                                 Kmem + (size_t)d * NTOK * DD,
                                                 Vmem + (size_t)d * NTOK * D2,
                                                 d < NDEPTH - 1 ? 1 : 0);
        { float* t = cur; cur = oth; oth = t; }
    }

    // cur = z after look-1 cell (written by depth-5 finishG). Two more look cells:
    for (int l = 1; l < NLOOK; ++l) {
        gemmT_kernel<128><<<dim3(16, 4, 8), 256, 0, stream>>>(CW, cur, bigP, D2);
        epi_kernel<<<dim3(2, 256), 256, 0, stream>>>(bigP, oth);
        { float* t = cur; cur = oth; oth = t; }
    }

    // ---------- decode ----------
    gemmT_kernel<64><<<dim3(4, 4, 16), 256, 0, stream>>>(decT, cur, decP, VOCAB);
    deccomb_kernel<<<256, 256, 0, stream>>>(decP, dec_b, rows);
    scatterloss_kernel<<<BS_TOT / 4 + 1, 256, 0, stream>>>(x, rows, out, symErr, conErr);
}

// Round 13
// 438.491 us; speedup vs baseline: 2.4841x; 1.0200x over previous
//
#include <hip/hip_runtime.h>
#include <math.h>

// Problem constants
constexpr int DD    = 512;     // D
constexpr int D2    = 1024;    // 2D
constexpr int NTOK  = 256;     // vocab V (unique tokens = unique pipelines)
constexpr int NSYM  = 512;
constexpr int NCON  = 64;
constexpr int VOCAB = 256;
constexpr int BS_TOT = 32 * 512;   // B*S = 16384
constexpr int NDEPTH = 6;
constexpr int NLOOK  = 3;
constexpr float EPSF = 1e-8f;
constexpr float SCALE = 0.044194173824159216f; // 512^-0.5

__device__ inline void fma4(float4& a, const float4& w, float s) {
    a.x += w.x * s; a.y += w.y * s; a.z += w.z * s; a.w += w.w * s;
}

__device__ inline float wave_sum(float x) {
#pragma unroll
    for (int off = 32; off; off >>= 1) x += __shfl_xor(x, off, 64);
    return x;
}

__device__ inline void wave_argmin(float& d, int& i) {
#pragma unroll
    for (int off = 32; off; off >>= 1) {
        float od = __shfl_xor(d, off, 64);
        int   oi = __shfl_xor(i, off, 64);
        if (od < d || (od == d && oi < i)) { d = od; i = oi; }
    }
}

// ================= verified GEMM body (64t x 64j, dbuf, 1 barrier/chunk) =====
// X: [M][1024] t-major. WT: [1024][N] k-major. P[slot][mstr][N].
__device__ __forceinline__ void d_gemmT(const float* __restrict__ WT,
                                        const float* __restrict__ X,
                                        float* __restrict__ P, int N,
                                        int j0, int t0, int k0, int NC, int slot,
                                        int mstr,
                                        float* __restrict__ sX, float* __restrict__ sW) {
    constexpr int LDT = 68;
    int tid = threadIdx.x;
    int jq = tid & 15;
    int tq = tid >> 4;
    int f0 = tid * 2, f1 = tid * 2 + 1;
    int tA0 = f0 >> 3, kqA0 = f0 & 7;
    int tA1 = f1 >> 3, kqA1 = f1 & 7;
    int kwB0 = f0 >> 4, jB0 = f0 & 15;
    int kwB1 = f1 >> 4, jB1 = f1 & 15;
    float4 vx0, vx1, vw0, vw1;

#define GLOAD(kbase) do { \
        vx0 = *(const float4*)&X[(size_t)(t0 + tA0) * D2 + (kbase) + kqA0 * 4]; \
        vx1 = *(const float4*)&X[(size_t)(t0 + tA1) * D2 + (kbase) + kqA1 * 4]; \
        vw0 = *(const float4*)&WT[(size_t)((kbase) + kwB0) * N + j0 + jB0 * 4]; \
        vw1 = *(const float4*)&WT[(size_t)((kbase) + kwB1) * N + j0 + jB1 * 4]; \
    } while (0)
#define LSTORE(bufi) do { \
        float* sxB = sX + (bufi) * 2176; float* swB = sW + (bufi) * 2176; \
        sxB[(kqA0 * 4 + 0) * LDT + tA0] = vx0.x; \
        sxB[(kqA0 * 4 + 1) * LDT + tA0] = vx0.y; \
        sxB[(kqA0 * 4 + 2) * LDT + tA0] = vx0.z; \
        sxB[(kqA0 * 4 + 3) * LDT + tA0] = vx0.w; \
        sxB[(kqA1 * 4 + 0) * LDT + tA1] = vx1.x; \
        sxB[(kqA1 * 4 + 1) * LDT + tA1] = vx1.y; \
        sxB[(kqA1 * 4 + 2) * LDT + tA1] = vx1.z; \
        sxB[(kqA1 * 4 + 3) * LDT + tA1] = vx1.w; \
        *(float4*)&swB[kwB0 * LDT + jB0 * 4] = vw0; \
        *(float4*)&swB[kwB1 * LDT + jB1 * 4] = vw1; \
    } while (0)

    float4 acc0 = {0,0,0,0}, acc1 = {0,0,0,0}, acc2 = {0,0,0,0}, acc3 = {0,0,0,0};

    GLOAD(k0);
    LSTORE(0);
    __syncthreads();

    for (int kc = 0; kc < NC; ++kc) {
        if (kc + 1 < NC) GLOAD(k0 + (kc + 1) * 32);
        const float* sxB = sX + (kc & 1) * 2176;
        const float* swB = sW + (kc & 1) * 2176;
#pragma unroll 8
        for (int k = 0; k < 32; ++k) {
            float4 xa = *(const float4*)&sxB[k * LDT + tq * 4];
            float4 wb = *(const float4*)&swB[k * LDT + jq * 4];
            fma4(acc0, wb, xa.x);
            fma4(acc1, wb, xa.y);
            fma4(acc2, wb, xa.z);
            fma4(acc3, wb, xa.w);
        }
        if (kc + 1 < NC) LSTORE((kc + 1) & 1);
        __syncthreads();
    }
#undef GLOAD
#undef LSTORE

    size_t base = ((size_t)slot * mstr + (t0 + tq * 4)) * N + j0 + jq * 4;
    *(float4*)&P[base]         = acc0;
    *(float4*)&P[base + N]     = acc1;
    *(float4*)&P[base + 2*N]   = acc2;
    *(float4*)&P[base + 3*N]   = acc3;
}

// generic GEMM launch: grid (N/64, 4, S); K-slice = KB per z-slot
template<int KB>
__global__ __launch_bounds__(256) void gemmT_kernel(const float* __restrict__ WT,
                                                    const float* __restrict__ X,
                                                    float* __restrict__ P,
                                                    int N) {
    __shared__ __align__(16) float sX[2 * 2176];
    __shared__ __align__(16) float sW[2 * 2176];
    d_gemmT(WT, X, P, N, blockIdx.x * 64, blockIdx.y * 64,
            blockIdx.z * KB, KB / 32, blockIdx.z, NTOK, sX, sW);
}

// ---- precompute partials: SCP = sym @ CW (split-4), SKVP = sym @ KVT (split-2) ----
// grid 896 flat: blocks [0,512) SC (128 tiles x 4 splits, NC=8);
//                blocks [512,896) SKV (192 tiles x 2 splits, NC=16).
__global__ __launch_bounds__(256) void precomp2_kernel(const float* __restrict__ CW,
                                                       const float* __restrict__ KVT,
                                                       const float* __restrict__ sym,
                                                       float* __restrict__ SCP,
                                                       float* __restrict__ SKVP) {
    __shared__ __align__(16) float sX[2 * 2176];
    __shared__ __align__(16) float sW[2 * 2176];
    int b = blockIdx.x;
    if (b < 512) {
        int s = b & 3, tile = b >> 2;          // tile in [0,128)
        int jx = tile & 15, tx = tile >> 4;
        d_gemmT(CW, sym, SCP, 1024, jx * 64, tx * 64, s * 256, 8, s, NSYM, sX, sW);
    } else {
        int q = b - 512;
        int s = q & 1, tile = q >> 1;          // tile in [0,192)
        int jx = tile % 24, tx = tile / 24;
        d_gemmT(KVT, sym, SKVP, 1536, jx * 64, tx * 64, s * 512, 16, s, NSYM, sX, sW);
    }
}

// ---- combine: SC = sum4 SCP (ascending s); SKV = sum2 SKVP. grid 1024, block 256 ----
__global__ __launch_bounds__(256) void precombine_kernel(const float* __restrict__ SCP,
                                                         const float* __restrict__ SKVP,
                                                         float* __restrict__ SC,
                                                         float* __restrict__ SKV) {
    int b = blockIdx.x, tid = threadIdx.x;
    if (b < 512) {
        int c = b;
#pragma unroll
        for (int r = 0; r < 4; ++r) {
            int j = r * 256 + tid;
            float v = 0.f;
#pragma unroll
            for (int s = 0; s < 4; ++s)
                v += SCP[((size_t)s * NSYM + c) * 1024 + j];
            SC[(size_t)c * 1024 + j] = v;
        }
    } else {
        int c = b - 512;
#pragma unroll
        for (int r = 0; r < 6; ++r) {
            int e = r * 256 + tid;
            float v = SKVP[(size_t)c * 1536 + e]
                    + SKVP[((size_t)NSYM + c) * 1536 + e];
            SKV[(size_t)c * 1536 + e] = v;
        }
    }
}

// ---------------- cell epilogue: combine 8 partials + tanh-norm. grid (2,256) --------
__global__ __launch_bounds__(256) void epi_kernel(const float* __restrict__ cellP,
                                                  float* __restrict__ z) {
    int bx = blockIdx.x, t = blockIdx.y, tid = threadIdx.x;
    int j = bx * 256 + tid;
    float lr = 0.f, li = 0.f;
#pragma unroll
    for (int s = 0; s < 8; ++s) {
        lr += cellP[((size_t)s * NTOK + t) * D2 + j];
        li += cellP[((size_t)s * NTOK + t) * D2 + DD + j];
    }
    float m = sqrtf(lr * lr + li * li + EPSF);
    float inv = 1.0f / (1.0f + m);
    z[(size_t)t * D2 + j]      = tanhf(lr * inv);
    z[(size_t)t * D2 + DD + j] = tanhf(li * inv);
}

// ---------------- attend: wave-shuffle reduce, softmax, ctx (8 QP partials) ----------------
__global__ __launch_bounds__(256) void attend8_kernel(float* __restrict__ z,
                                                      const float* __restrict__ QP,
                                                      const float* __restrict__ qb,
                                                      const float* __restrict__ Kmem,
                                                      const float* __restrict__ Vmem,
                                                      const float* __restrict__ conf,
                                                      int M) {
    int v = blockIdx.x, tid = threadIdx.x;
    int lane = tid & 63, w = tid >> 6;
    __shared__ float s_part[4][5];
    float q0 = 0.f, q1 = 0.f;
#pragma unroll
    for (int s = 0; s < 8; ++s) {
        q0 += QP[((size_t)s * NTOK + v) * DD + tid];
        q1 += QP[((size_t)s * NTOK + v) * DD + 256 + tid];
    }
    q0 += qb[tid];
    q1 += qb[256 + tid];
    float sc[5];
#pragma unroll
    for (int m = 0; m < 5; ++m) {
        if (m < M) {
            const float* K = Kmem + (size_t)m * NTOK * DD + (size_t)v * DD;
            sc[m] = q0 * K[tid] + q1 * K[256 + tid];
        } else sc[m] = 0.f;
    }
#pragma unroll
    for (int m = 0; m < 5; ++m) {
        if (m < M) {
            float x = wave_sum(sc[m]);
            if (lane == 0) s_part[w][m] = x;
        }
    }
    __syncthreads();
    float cf = conf[v];
    float scf[5];
    float mx = -1e30f;
#pragma unroll
    for (int m = 0; m < 5; ++m) {
        if (m < M) {
            float t = (s_part[0][m] + s_part[1][m] + s_part[2][m] + s_part[3][m]) * SCALE * cf;
            scf[m] = t;
            mx = fmaxf(mx, t);
        }
    }
    float sum = 0.f;
#pragma unroll
    for (int m = 0; m < 5; ++m) {
        if (m < M) { scf[m] = expf(scf[m] - mx); sum += scf[m]; }
    }
    float inv = 1.0f / sum;
#pragma unroll
    for (int r = 0; r < 4; ++r) {
        int e = r * 256 + tid;
        float ctx = 0.f;
#pragma unroll
        for (int m = 0; m < 5; ++m)
            if (m < M) ctx += scf[m] * Vmem[(size_t)m * NTOK * D2 + (size_t)v * D2 + e];
        z[(size_t)v * D2 + e] += 0.1f * ctx * inv;
    }
}

// ------- finishG: round-9 finish + fused next-cell gather (SC) + KV gather (SKV) -------
__global__ __launch_bounds__(512) void finishG_kernel(const float* __restrict__ z,
                                                      const float* __restrict__ sym,
                                                      const float* __restrict__ snorm,
                                                      const float* __restrict__ con,
                                                      const float* __restrict__ conT,
                                                      const float* __restrict__ symP,
                                                      float* __restrict__ conf,
                                                      float* __restrict__ symErr,
                                                      float* __restrict__ conErr,
                                                      const float* __restrict__ SC,
                                                      const float* __restrict__ SKV,
                                                      float* __restrict__ zmid,
                                                      const float* __restrict__ kb,
                                                      const float* __restrict__ vb,
                                                      float* __restrict__ Kslot,
                                                      float* __restrict__ Vslot,
                                                      int doKV) {
    int t0 = blockIdx.x, tid = threadIdx.x;
    int lane = tid & 63, w = tid >> 6;
    __shared__ __align__(16) float s_z[D2];
    __shared__ float wA[8];
    __shared__ float wB[8]; __shared__ int wiB[8];
    __shared__ float wC[8], wD[8];
    __shared__ float wE[8];
    __shared__ int   s_ci[1];
    __shared__ float s_pd[512], s_pc[512];

    if (tid < 256) ((float4*)s_z)[tid] = ((const float4*)(z + (size_t)t0 * D2))[tid];
    __syncthreads();
    {
        float a = s_z[tid], b = s_z[512 + tid];
        float nrm = wave_sum(a * a + b * b);
        if (lane == 0) wA[w] = nrm;
    }
    __syncthreads();
    float znorm = 0.f;
#pragma unroll
    for (int k = 0; k < 8; ++k) znorm += wA[k];
    {
        float dot = 0.f;
#pragma unroll
        for (int s = 0; s < 8; ++s)
            dot += symP[((size_t)s * NTOK + t0) * NSYM + tid];
        float d = (znorm + snorm[tid]) - 2.f * dot;
        int idx = tid;
        wave_argmin(d, idx);
        if (lane == 0) { wB[w] = d; wiB[w] = idx; }
    }
    __syncthreads();
    float dmin = wB[0]; int si = wiB[0];
#pragma unroll
    for (int k = 1; k < 8; ++k) {
        if (wB[k] < dmin || (wB[k] == dmin && wiB[k] < si)) { dmin = wB[k]; si = wiB[k]; }
    }
    if (tid == 0) conf[t0] = 1.0f / (1.0f + dmin);
    // straight-through (in s_z only; zs never stored) + symErr + ||zs||^2
    {
        const float* crow = sym + (size_t)si * D2;
        float errp = 0.f, zn2 = 0.f;
#pragma unroll
        for (int r = 0; r < 2; ++r) {
            int e = r * 512 + tid;
            float zf = s_z[e];
            float diff = crow[e] - zf;
            errp += diff * diff;
            float zn = zf + diff;
            zn2 += zn * zn;
            s_z[e] = zn;
        }
        errp = wave_sum(errp);
        zn2  = wave_sum(zn2);
        if (lane == 0) { wC[w] = errp; wD[w] = zn2; }
    }
    __syncthreads();
    if (tid == 0) {
        float s = 0.f;
#pragma unroll
        for (int k = 0; k < 8; ++k) s += wC[k];
        symErr[t0] += s;
    }
    float zsnorm = 0.f;
#pragma unroll
    for (int k = 0; k < 8; ++k) zsnorm += wD[k];
    {
        int c = tid & 63, sl = tid >> 6;
        float pd = 0.f, pc = 0.f;
        int kk0 = sl * 128;
#pragma unroll 4
        for (int k = kk0; k < kk0 + 128; ++k) {
            float wv = conT[(size_t)k * NCON + c];
            pd += wv * s_z[k];
            pc += wv * wv;
        }
        s_pd[tid] = pd; s_pc[tid] = pc;
    }
    __syncthreads();
    if (tid < 64) {
        float dot2 = 0.f, cn2 = 0.f;
#pragma unroll
        for (int i = 0; i < 8; ++i) { dot2 += s_pd[tid + 64 * i]; cn2 += s_pc[tid + 64 * i]; }
        float dc = (zsnorm + cn2) - 2.f * dot2;
        int ic = tid;
        wave_argmin(dc, ic);
        if (tid == 0) s_ci[0] = ic;
    }
    __syncthreads();
    int ci0 = s_ci[0];
    {
        const float* crow = con + (size_t)ci0 * D2;
        float p = 0.f;
#pragma unroll
        for (int r = 0; r < 2; ++r) {
            int e = r * 512 + tid;
            float diff = crow[e] - s_z[e];
            p += diff * diff;
        }
        p = wave_sum(p);
        if (lane == 0) wE[w] = p;
    }
    __syncthreads();
    if (tid == 0) {
        float s = 0.f;
#pragma unroll
        for (int k = 0; k < 8; ++k) s += wE[k];
        conErr[t0] += s;
    }

    // ---- fused tail: next-cell gather + tanh-norm, and KV slot gather + bias ----
    {
        const float* scr = SC + (size_t)si * D2;
        int j = tid;                       // 0..511
        float lr = scr[j], li = scr[j + DD];
        float m = sqrtf(lr * lr + li * li + EPSF);
        float inv = 1.0f / (1.0f + m);
        zmid[(size_t)t0 * D2 + j]      = tanhf(lr * inv);
        zmid[(size_t)t0 * D2 + DD + j] = tanhf(li * inv);
        if (doKV) {
            const float* skr = SKV + (size_t)si * 1536;
#pragma unroll
            for (int it = 0; it < 3; ++it) {
                int e = it * 512 + tid;
                float v = skr[e];
                if (e < DD) Kslot[(size_t)t0 * DD + e]        = v + kb[e];
                else        Vslot[(size_t)t0 * D2 + (e - DD)] = v + vb[e - DD];
            }
        }
    }
}

// ---------------- dec combine: rows = sum of 16 partials + dec_b ----------------
__global__ void deccomb_kernel(const float* __restrict__ P, const float* __restrict__ db,
                               float* __restrict__ rows) {
    int t = blockIdx.x, j = threadIdx.x;
    float v = 0.f;
#pragma unroll
    for (int s = 0; s < 16; ++s)
        v += P[((size_t)s * NTOK + t) * VOCAB + j];
    rows[(size_t)t * VOCAB + j] = v + db[j];
}

// ---------------- scatter + in-block hist + loss (last block) ----------------
__global__ __launch_bounds__(256) void scatterloss_kernel(const int* __restrict__ x,
                                                          const float* __restrict__ rows,
                                                          float* __restrict__ out,
                                                          const float* __restrict__ symErr,
                                                          const float* __restrict__ conErr) {
    int tid = threadIdx.x;
    if (blockIdx.x == BS_TOT / 4) {
        __shared__ int h[256];
        __shared__ double rs[256], rc[256];
        h[tid] = 0;
        __syncthreads();
        for (int i = tid; i < BS_TOT; i += 256) atomicAdd(&h[x[i]], 1);
        __syncthreads();
        rs[tid] = (double)h[tid] * (double)symErr[tid];
        rc[tid] = (double)h[tid] * (double)conErr[tid];
        __syncthreads();
        for (int off = 128; off > 0; off >>= 1) {
            if (tid < off) { rs[tid] += rs[tid + off]; rc[tid] += rc[tid + off]; }
            __syncthreads();
        }
        if (tid == 0) {
            const double denom = (double)BS_TOT * (double)D2;
            out[(size_t)BS_TOT * VOCAB]     = (float)(1.25 * rs[0] / denom);
            out[(size_t)BS_TOT * VOCAB + 1] = (float)(1.25 * rc[0] / denom);
        }
        return;
    }
    int pos = blockIdx.x * 4 + (tid >> 6);
    int lane = tid & 63;
    int v = x[pos];
    const float4* r = (const float4*)(rows + (size_t)v * VOCAB);
    ((float4*)(out + (size_t)pos * VOCAB))[lane] = r[lane];
}

// ---------------- fused setup: 6 transposes + zero + buildcw + embed + symnorm ----------
// grid 3905, block 512 flat.
__global__ __launch_bounds__(512) void setup_kernel(const float* __restrict__ qw,
                                                    const float* __restrict__ kw,
                                                    const float* __restrict__ vw,
                                                    const float* __restrict__ sym,
                                                    const float* __restrict__ dec_w,
                                                    const float* __restrict__ con,
                                                    const float* __restrict__ Wr,
                                                    const float* __restrict__ Wi,
                                                    const float* __restrict__ mag,
                                                    const float* __restrict__ phase,
                                                    float* __restrict__ qwT,
                                                    float* __restrict__ KVT,
                                                    float* __restrict__ symT,
                                                    float* __restrict__ decT,
                                                    float* __restrict__ conT,
                                                    float* __restrict__ CW,
                                                    float* __restrict__ dst,
                                                    float* __restrict__ snorm,
                                                    float* __restrict__ symErr,
                                                    float* __restrict__ conErr) {
    __shared__ float t[32][33];
    __shared__ float tr[32][33], ti[32][33];
    __shared__ float s_w[8];
    int b = blockIdx.x;
    int tid = threadIdx.x;

    if (b < 2880) {   // transposes (all sources have 1024 columns)
        const float* in; float* outp; int ldo;
        if      (b < 512)  {           in = qw;    outp = qwT;      ldo = DD;    }
        else if (b < 1024) { b -= 512; in = kw;    outp = KVT;      ldo = 1536;  }
        else if (b < 2048) { b -= 1024; in = vw;   outp = KVT + DD; ldo = 1536;  }
        else if (b < 2560) { b -= 2048; in = sym;  outp = symT;     ldo = NSYM;  }
        else if (b < 2816) { b -= 2560; in = dec_w; outp = decT;    ldo = VOCAB; }
        else               { b -= 2816; in = con;  outp = conT;     ldo = NCON;  }
        int bx = b & 31, by = b >> 5;
        int c0 = bx * 32, r0 = by * 32;
        int xx = tid & 31, yy = tid >> 5;   // yy in 0..15
#pragma unroll
        for (int i = 0; i < 32; i += 16)
            t[yy + i][xx] = in[(size_t)(r0 + yy + i) * D2 + c0 + xx];
        __syncthreads();
#pragma unroll
        for (int i = 0; i < 32; i += 16)
            outp[(size_t)(c0 + yy + i) * ldo + r0 + xx] = t[xx][yy + i];
        return;
    }
    if (b == 2880) {
        if (tid < 256) { symErr[tid] = 0.f; conErr[tid] = 0.f; }
        return;
    }
    if (b < 3137) {   // buildcw, 256 blocks
        int q = b - 2881;
        int j0 = (q & 15) * 32, k0 = (q >> 4) * 32;
        int xx = tid & 31, yy = tid >> 5;
#pragma unroll
        for (int i = 0; i < 32; i += 16) {
            tr[yy + i][xx] = Wr[(size_t)(j0 + yy + i) * DD + k0 + xx];
            ti[yy + i][xx] = Wi[(size_t)(j0 + yy + i) * DD + k0 + xx];
        }
        __syncthreads();
#pragma unroll
        for (int i = 0; i < 32; i += 16) {
            float vr = tr[xx][yy + i];
            float vi = ti[xx][yy + i];
            int k = k0 + yy + i, j = j0 + xx;
            CW[(size_t)k * D2 + j]             = vr;
            CW[(size_t)k * D2 + DD + j]        = vi;
            CW[(size_t)(DD + k) * D2 + j]      = -vi;
            CW[(size_t)(DD + k) * D2 + DD + j] = vr;
        }
        return;
    }
    if (b < 3393) {   // embed, 256 blocks, 512 threads = 512 j
        int v = b - 3137, j = tid;
        float r = mag[v * DD + j], th = phase[v * DD + j];
        dst[(size_t)v * D2 + j]      = r * cosf(th);
        dst[(size_t)v * D2 + DD + j] = r * sinf(th);
        return;
    }
    {   // symnorm, 512 blocks
        int c = b - 3393;
        float2 vv = ((const float2*)(sym + (size_t)c * D2))[tid];
        float p = vv.x * vv.x + vv.y * vv.y;
        p = wave_sum(p);
        int lane = tid & 63, w = tid >> 6;
        if (lane == 0) s_w[w] = p;
        __syncthreads();
        if (tid == 0) {
            float s = 0.f;
#pragma unroll
            for (int k = 0; k < 8; ++k) s += s_w[k];
            snorm[c] = s;
        }
    }
}

// ---------------- host ----------------
extern "C" void kernel_launch(void* const* d_in, const int* in_sizes, int n_in,
                              void* d_out, int out_size, void* d_ws, size_t ws_size,
                              hipStream_t stream) {
    const int*   x     = (const int*)  d_in[0];
    const float* mag   = (const float*)d_in[1];
    const float* phase = (const float*)d_in[2];
    const float* Wr    = (const float*)d_in[3];
    const float* Wi    = (const float*)d_in[4];
    const float* qw    = (const float*)d_in[5];
    const float* qb    = (const float*)d_in[6];
    const float* kw    = (const float*)d_in[7];
    const float* kb    = (const float*)d_in[8];
    const float* vw    = (const float*)d_in[9];
    const float* vb    = (const float*)d_in[10];
    const float* dec_w = (const float*)d_in[11];
    const float* dec_b = (const float*)d_in[12];
    const float* sym   = (const float*)d_in[13];
    const float* con   = (const float*)d_in[14];
    float* out = (float*)d_out;

    // workspace layout (floats); total ~42.5 MB (SC/SKV reuse old kvP region)
    float* ws     = (float*)d_ws;
    float* bufA   = ws;                          // 262144
    float* bufB   = bufA + NTOK * D2;            // 262144
    float* Kmem   = bufB + NTOK * D2;            // 786432
    float* Vmem   = Kmem + NDEPTH * NTOK * DD;   // 1572864
    float* rows   = Vmem + NDEPTH * NTOK * D2;   // 65536
    float* CW     = rows + NTOK * VOCAB;         // 1048576
    float* qwT    = CW + D2 * D2;                // 524288
    float* KVT    = qwT + D2 * DD;               // 1572864
    float* symT   = KVT + D2 * 1536;             // 524288
    float* decT   = symT + D2 * NSYM;            // 262144
    float* conT   = decT + D2 * VOCAB;           // 65536
    float* bigP   = conT + D2 * NCON;            // 2097152
    float* SC     = bigP + 8 * NTOK * D2;        // 524288  (old kvP region)
    float* SKV    = SC + NSYM * D2;              // 786432  (fits in old kvP 1572864)
    float* snorm  = bigP + 8 * NTOK * D2 + 4 * NTOK * 1536;  // 512 (unchanged offset)
    float* conf   = snorm + NSYM;                // 256
    float* symErr = conf + NTOK;                 // 256
    float* conErr = symErr + NTOK;               // 256

    float* QP   = bigP;                 // 8*256*512
    float* symP = bigP + 1048576;       // 8*256*512
    float* decP = bigP;                 // 16*256*256

    // precomp scratch (live only between precomp2 and precombine):
    float* SCP  = bigP;                 // 4*512*1024 = 2097152 (== bigP size)
    float* SKVP = Vmem;                 // 2*512*1536 = 1572864 (== Vmem size; Vmem
                                        //   first written by finishG(d0), later)

    setup_kernel<<<3905, 512, 0, stream>>>(qw, kw, vw, sym, dec_w, con, Wr, Wi, mag, phase,
                                           qwT, KVT, symT, decT, conT, CW,
                                           bufA, snorm, symErr, conErr);
    precomp2_kernel<<<896, 256, 0, stream>>>(CW, KVT, sym, SCP, SKVP);
    precombine_kernel<<<1024, 256, 0, stream>>>(SCP, SKVP, SC, SKV);

    // ---------- d = 0: real cell GEMM (embed input), then sym + finishG ----------
    gemmT_kernel<128><<<dim3(16, 4, 8), 256, 0, stream>>>(CW, bufA, bigP, D2);
    epi_kernel<<<dim3(2, 256), 256, 0, stream>>>(bigP, bufB);
    gemmT_kernel<128><<<dim3(8, 4, 8), 256, 0, stream>>>(symT, bufB, symP, NSYM);
    finishG_kernel<<<NTOK, 512, 0, stream>>>(bufB, sym, snorm, con, conT, symP,
                                             conf, symErr, conErr,
                                             SC, SKV, bufA, kb, vb,
                                             Kmem, Vmem, 1);
    float* cur = bufA;   // z_mid for depth 1
    float* oth = bufB;

    // ---------- d = 1..5: qgemm -> attend -> symgemm -> finishG (cell+KV fused) ------
    for (int d = 1; d < NDEPTH; ++d) {
        gemmT_kernel<128><<<dim3(8, 4, 8), 256, 0, stream>>>(qwT, cur, QP, DD);
        attend8_kernel<<<NTOK, 256, 0, stream>>>(cur, QP, qb, Kmem, Vmem, conf, d);
        gemmT_kernel<128><<<dim3(8, 4, 8), 256, 0, stream>>>(symT, cur, symP, NSYM);
        finishG_kernel<<<NTOK, 512, 0, stream>>>(cur, sym, snorm, con, conT, symP,
                                                 conf, symErr, conErr,
                                                 SC, SKV, oth, kb, vb,
                                                 Kmem + (size_t)d * NTOK * DD,
                                                 Vmem + (size_t)d * NTOK * D2,
                                                 d < NDEPTH - 1 ? 1 : 0);
        { float* t = cur; cur = oth; oth = t; }
    }

    // cur = z after look-1 cell (written by depth-5 finishG). Two more look cells:
    for (int l = 1; l < NLOOK; ++l) {
        gemmT_kernel<128><<<dim3(16, 4, 8), 256, 0, stream>>>(CW, cur, bigP, D2);
        epi_kernel<<<dim3(2, 256), 256, 0, stream>>>(bigP, oth);
        { float* t = cur; cur = oth; oth = t; }
    }

    // ---------- decode ----------
    gemmT_kernel<64><<<dim3(4, 4, 16), 256, 0, stream>>>(decT, cur, decP, VOCAB);
    deccomb_kernel<<<256, 256, 0, stream>>>(decP, dec_b, rows);
    scatterloss_kernel<<<BS_TOT / 4 + 1, 256, 0, stream>>>(x, rows, out, symErr, conErr);
}

// Round 14
// 406.339 us; speedup vs baseline: 2.6807x; 1.0791x over previous
//
#include <hip/hip_runtime.h>
#include <math.h>

// Problem constants
constexpr int DD    = 512;     // D
constexpr int D2    = 1024;    // 2D
constexpr int NTOK  = 256;     // vocab V (unique tokens = unique pipelines)
constexpr int NSYM  = 512;
constexpr int NCON  = 64;
constexpr int VOCAB = 256;
constexpr int BS_TOT = 32 * 512;   // B*S = 16384
constexpr int NDEPTH = 6;
constexpr int NLOOK  = 3;
constexpr float EPSF = 1e-8f;
constexpr float SCALE = 0.044194173824159216f; // 512^-0.5

__device__ inline void fma4(float4& a, const float4& w, float s) {
    a.x += w.x * s; a.y += w.y * s; a.z += w.z * s; a.w += w.w * s;
}

__device__ inline float wave_sum(float x) {
#pragma unroll
    for (int off = 32; off; off >>= 1) x += __shfl_xor(x, off, 64);
    return x;
}

__device__ inline void wave_argmin(float& d, int& i) {
#pragma unroll
    for (int off = 32; off; off >>= 1) {
        float od = __shfl_xor(d, off, 64);
        int   oi = __shfl_xor(i, off, 64);
        if (od < d || (od == d && oi < i)) { d = od; i = oi; }
    }
}

// ================= verified GEMM body (64t x 64j, dbuf, 1 barrier/chunk) =====
// X: [M][1024] t-major. WT: [1024][N] k-major. P[slot][mstr][N].
__device__ __forceinline__ void d_gemmT(const float* __restrict__ WT,
                                        const float* __restrict__ X,
                                        float* __restrict__ P, int N,
                                        int j0, int t0, int k0, int NC, int slot,
                                        int mstr,
                                        float* __restrict__ sX, float* __restrict__ sW) {
    constexpr int LDT = 68;
    int tid = threadIdx.x;
    int jq = tid & 15;
    int tq = tid >> 4;
    int f0 = tid * 2, f1 = tid * 2 + 1;
    int tA0 = f0 >> 3, kqA0 = f0 & 7;
    int tA1 = f1 >> 3, kqA1 = f1 & 7;
    int kwB0 = f0 >> 4, jB0 = f0 & 15;
    int kwB1 = f1 >> 4, jB1 = f1 & 15;
    float4 vx0, vx1, vw0, vw1;

#define GLOAD(kbase) do { \
        vx0 = *(const float4*)&X[(size_t)(t0 + tA0) * D2 + (kbase) + kqA0 * 4]; \
        vx1 = *(const float4*)&X[(size_t)(t0 + tA1) * D2 + (kbase) + kqA1 * 4]; \
        vw0 = *(const float4*)&WT[(size_t)((kbase) + kwB0) * N + j0 + jB0 * 4]; \
        vw1 = *(const float4*)&WT[(size_t)((kbase) + kwB1) * N + j0 + jB1 * 4]; \
    } while (0)
#define LSTORE(bufi) do { \
        float* sxB = sX + (bufi) * 2176; float* swB = sW + (bufi) * 2176; \
        sxB[(kqA0 * 4 + 0) * LDT + tA0] = vx0.x; \
        sxB[(kqA0 * 4 + 1) * LDT + tA0] = vx0.y; \
        sxB[(kqA0 * 4 + 2) * LDT + tA0] = vx0.z; \
        sxB[(kqA0 * 4 + 3) * LDT + tA0] = vx0.w; \
        sxB[(kqA1 * 4 + 0) * LDT + tA1] = vx1.x; \
        sxB[(kqA1 * 4 + 1) * LDT + tA1] = vx1.y; \
        sxB[(kqA1 * 4 + 2) * LDT + tA1] = vx1.z; \
        sxB[(kqA1 * 4 + 3) * LDT + tA1] = vx1.w; \
        *(float4*)&swB[kwB0 * LDT + jB0 * 4] = vw0; \
        *(float4*)&swB[kwB1 * LDT + jB1 * 4] = vw1; \
    } while (0)

    float4 acc0 = {0,0,0,0}, acc1 = {0,0,0,0}, acc2 = {0,0,0,0}, acc3 = {0,0,0,0};

    GLOAD(k0);
    LSTORE(0);
    __syncthreads();

    for (int kc = 0; kc < NC; ++kc) {
        if (kc + 1 < NC) GLOAD(k0 + (kc + 1) * 32);
        const float* sxB = sX + (kc & 1) * 2176;
        const float* swB = sW + (kc & 1) * 2176;
#pragma unroll 8
        for (int k = 0; k < 32; ++k) {
            float4 xa = *(const float4*)&sxB[k * LDT + tq * 4];
            float4 wb = *(const float4*)&swB[k * LDT + jq * 4];
            fma4(acc0, wb, xa.x);
            fma4(acc1, wb, xa.y);
            fma4(acc2, wb, xa.z);
            fma4(acc3, wb, xa.w);
        }
        if (kc + 1 < NC) LSTORE((kc + 1) & 1);
        __syncthreads();
    }
#undef GLOAD
#undef LSTORE

    size_t base = ((size_t)slot * mstr + (t0 + tq * 4)) * N + j0 + jq * 4;
    *(float4*)&P[base]         = acc0;
    *(float4*)&P[base + N]     = acc1;
    *(float4*)&P[base + 2*N]   = acc2;
    *(float4*)&P[base + 3*N]   = acc3;
}

// generic GEMM launch: grid (N/64, 4, S); K-slice = KB per z-slot
template<int KB>
__global__ __launch_bounds__(256) void gemmT_kernel(const float* __restrict__ WT,
                                                    const float* __restrict__ X,
                                                    float* __restrict__ P,
                                                    int N) {
    __shared__ __align__(16) float sX[2 * 2176];
    __shared__ __align__(16) float sW[2 * 2176];
    d_gemmT(WT, X, P, N, blockIdx.x * 64, blockIdx.y * 64,
            blockIdx.z * KB, KB / 32, blockIdx.z, NTOK, sX, sW);
}

// ---- precompute partials: SCP = sym @ CW (split-4), SKVP = sym @ KVT (split-2) ----
// grid 896 flat: blocks [0,512) SC (128 tiles x 4 splits, NC=8);
//                blocks [512,896) SKV (192 tiles x 2 splits, NC=16).
__global__ __launch_bounds__(256) void precomp2_kernel(const float* __restrict__ CW,
                                                       const float* __restrict__ KVT,
                                                       const float* __restrict__ sym,
                                                       float* __restrict__ SCP,
                                                       float* __restrict__ SKVP) {
    __shared__ __align__(16) float sX[2 * 2176];
    __shared__ __align__(16) float sW[2 * 2176];
    int b = blockIdx.x;
    if (b < 512) {
        int s = b & 3, tile = b >> 2;          // tile in [0,128)
        int jx = tile & 15, tx = tile >> 4;
        d_gemmT(CW, sym, SCP, 1024, jx * 64, tx * 64, s * 256, 8, s, NSYM, sX, sW);
    } else {
        int q = b - 512;
        int s = q & 1, tile = q >> 1;          // tile in [0,192)
        int jx = tile % 24, tx = tile / 24;
        d_gemmT(KVT, sym, SKVP, 1536, jx * 64, tx * 64, s * 512, 16, s, NSYM, sX, sW);
    }
}

// ---- combine: ZMID = tanh-norm(sum4 SCP) (ascending s); SKV = sum2 SKVP. -----------
// grid 1024, block 256. ZMID holds tanh-normed cell output for each of 512 codes —
// bitwise identical to old per-token tanh-norm(SC[si]) (same sums, same expressions).
__global__ __launch_bounds__(256) void precombine2_kernel(const float* __restrict__ SCP,
                                                          const float* __restrict__ SKVP,
                                                          float* __restrict__ ZMID,
                                                          float* __restrict__ SKV) {
    int b = blockIdx.x, tid = threadIdx.x;
    if (b < 512) {
        int c = b;
#pragma unroll
        for (int r = 0; r < 2; ++r) {
            int j = r * 256 + tid;        // j in [0,512)
            float lr = 0.f, li = 0.f;
#pragma unroll
            for (int s = 0; s < 4; ++s) {
                lr += SCP[((size_t)s * NSYM + c) * 1024 + j];
                li += SCP[((size_t)s * NSYM + c) * 1024 + j + DD];
            }
            float m = sqrtf(lr * lr + li * li + EPSF);
            float inv = 1.0f / (1.0f + m);
            ZMID[(size_t)c * D2 + j]      = tanhf(lr * inv);
            ZMID[(size_t)c * D2 + j + DD] = tanhf(li * inv);
        }
    } else {
        int c = b - 512;
#pragma unroll
        for (int r = 0; r < 6; ++r) {
            int e = r * 256 + tid;
            float v = SKVP[(size_t)c * 1536 + e]
                    + SKVP[((size_t)NSYM + c) * 1536 + e];
            SKV[(size_t)c * 1536 + e] = v;
        }
    }
}

// ---- symzq: d0 sym GEMM (blocks [0,256)) + ZQ = ZMID @ qwT split-4 ([256,512)) ----
__global__ __launch_bounds__(256) void symzq_kernel(const float* __restrict__ symT,
                                                    const float* __restrict__ X,
                                                    float* __restrict__ symP,
                                                    const float* __restrict__ qwT,
                                                    const float* __restrict__ ZMID,
                                                    float* __restrict__ ZQP) {
    __shared__ __align__(16) float sX[2 * 2176];
    __shared__ __align__(16) float sW[2 * 2176];
    int b = blockIdx.x;
    if (b < 256) {
        int jx = b & 7, tx = (b >> 3) & 3, s = b >> 5;
        d_gemmT(symT, X, symP, NSYM, jx * 64, tx * 64, s * 128, 4, s, NTOK, sX, sW);
    } else {
        int q = b - 256;
        int s = q & 3, tile = q >> 2;          // tile in [0,64)
        int jx = tile & 7, tx = tile >> 3;     // 8 x 8
        d_gemmT(qwT, ZMID, ZQP, DD, jx * 64, tx * 64, s * 256, 8, s, NSYM, sX, sW);
    }
}

// ---------------- cell epilogue: combine 8 partials + tanh-norm. grid (2,256) --------
__global__ __launch_bounds__(256) void epi_kernel(const float* __restrict__ cellP,
                                                  float* __restrict__ z) {
    int bx = blockIdx.x, t = blockIdx.y, tid = threadIdx.x;
    int j = bx * 256 + tid;
    float lr = 0.f, li = 0.f;
#pragma unroll
    for (int s = 0; s < 8; ++s) {
        lr += cellP[((size_t)s * NTOK + t) * D2 + j];
        li += cellP[((size_t)s * NTOK + t) * D2 + DD + j];
    }
    float m = sqrtf(lr * lr + li * li + EPSF);
    float inv = 1.0f / (1.0f + m);
    z[(size_t)t * D2 + j]      = tanhf(lr * inv);
    z[(size_t)t * D2 + DD + j] = tanhf(li * inv);
}

// ------- attendZ: Q gathered from ZQP via si (4 partials + qb), rest = attend8 -------
__global__ __launch_bounds__(256) void attendZ_kernel(float* __restrict__ z,
                                                      const float* __restrict__ ZQP,
                                                      const float* __restrict__ qb,
                                                      const float* __restrict__ Kmem,
                                                      const float* __restrict__ Vmem,
                                                      const float* __restrict__ conf,
                                                      const int* __restrict__ si,
                                                      int M) {
    int v = blockIdx.x, tid = threadIdx.x;
    int lane = tid & 63, w = tid >> 6;
    __shared__ float s_part[4][5];
    int sv = si[v];
    float q0 = 0.f, q1 = 0.f;
#pragma unroll
    for (int s = 0; s < 4; ++s) {
        q0 += ZQP[((size_t)s * NSYM + sv) * DD + tid];
        q1 += ZQP[((size_t)s * NSYM + sv) * DD + 256 + tid];
    }
    q0 += qb[tid];
    q1 += qb[256 + tid];
    float sc[5];
#pragma unroll
    for (int m = 0; m < 5; ++m) {
        if (m < M) {
            const float* K = Kmem + (size_t)m * NTOK * DD + (size_t)v * DD;
            sc[m] = q0 * K[tid] + q1 * K[256 + tid];
        } else sc[m] = 0.f;
    }
#pragma unroll
    for (int m = 0; m < 5; ++m) {
        if (m < M) {
            float x = wave_sum(sc[m]);
            if (lane == 0) s_part[w][m] = x;
        }
    }
    __syncthreads();
    float cf = conf[v];
    float scf[5];
    float mx = -1e30f;
#pragma unroll
    for (int m = 0; m < 5; ++m) {
        if (m < M) {
            float t = (s_part[0][m] + s_part[1][m] + s_part[2][m] + s_part[3][m]) * SCALE * cf;
            scf[m] = t;
            mx = fmaxf(mx, t);
        }
    }
    float sum = 0.f;
#pragma unroll
    for (int m = 0; m < 5; ++m) {
        if (m < M) { scf[m] = expf(scf[m] - mx); sum += scf[m]; }
    }
    float inv = 1.0f / sum;
#pragma unroll
    for (int r = 0; r < 4; ++r) {
        int e = r * 256 + tid;
        float ctx = 0.f;
#pragma unroll
        for (int m = 0; m < 5; ++m)
            if (m < M) ctx += scf[m] * Vmem[(size_t)m * NTOK * D2 + (size_t)v * D2 + e];
        z[(size_t)v * D2 + e] += 0.1f * ctx * inv;
    }
}

// ------- finishG2: finish + si store + zmid row-copy (ZMID) + KV gather (SKV) -------
__global__ __launch_bounds__(512) void finishG2_kernel(const float* __restrict__ z,
                                                       const float* __restrict__ sym,
                                                       const float* __restrict__ snorm,
                                                       const float* __restrict__ con,
                                                       const float* __restrict__ conT,
                                                       const float* __restrict__ symP,
                                                       float* __restrict__ conf,
                                                       float* __restrict__ symErr,
                                                       float* __restrict__ conErr,
                                                       const float* __restrict__ ZMID,
                                                       const float* __restrict__ SKV,
                                                       float* __restrict__ zmid,
                                                       const float* __restrict__ kb,
                                                       const float* __restrict__ vb,
                                                       float* __restrict__ Kslot,
                                                       float* __restrict__ Vslot,
                                                       int* __restrict__ siout,
                                                       int doKV) {
    int t0 = blockIdx.x, tid = threadIdx.x;
    int lane = tid & 63, w = tid >> 6;
    __shared__ __align__(16) float s_z[D2];
    __shared__ float wA[8];
    __shared__ float wB[8]; __shared__ int wiB[8];
    __shared__ float wC[8], wD[8];
    __shared__ float wE[8];
    __shared__ int   s_ci[1];
    __shared__ float s_pd[512], s_pc[512];

    if (tid < 256) ((float4*)s_z)[tid] = ((const float4*)(z + (size_t)t0 * D2))[tid];
    __syncthreads();
    {
        float a = s_z[tid], b = s_z[512 + tid];
        float nrm = wave_sum(a * a + b * b);
        if (lane == 0) wA[w] = nrm;
    }
    __syncthreads();
    float znorm = 0.f;
#pragma unroll
    for (int k = 0; k < 8; ++k) znorm += wA[k];
    {
        float dot = 0.f;
#pragma unroll
        for (int s = 0; s < 8; ++s)
            dot += symP[((size_t)s * NTOK + t0) * NSYM + tid];
        float d = (znorm + snorm[tid]) - 2.f * dot;
        int idx = tid;
        wave_argmin(d, idx);
        if (lane == 0) { wB[w] = d; wiB[w] = idx; }
    }
    __syncthreads();
    float dmin = wB[0]; int si = wiB[0];
#pragma unroll
    for (int k = 1; k < 8; ++k) {
        if (wB[k] < dmin || (wB[k] == dmin && wiB[k] < si)) { dmin = wB[k]; si = wiB[k]; }
    }
    if (tid == 0) { conf[t0] = 1.0f / (1.0f + dmin); siout[t0] = si; }
    // straight-through (in s_z only) + symErr + ||zs||^2
    {
        const float* crow = sym + (size_t)si * D2;
        float errp = 0.f, zn2 = 0.f;
#pragma unroll
        for (int r = 0; r < 2; ++r) {
            int e = r * 512 + tid;
            float zf = s_z[e];
            float diff = crow[e] - zf;
            errp += diff * diff;
            float zn = zf + diff;
            zn2 += zn * zn;
            s_z[e] = zn;
        }
        errp = wave_sum(errp);
        zn2  = wave_sum(zn2);
        if (lane == 0) { wC[w] = errp; wD[w] = zn2; }
    }
    __syncthreads();
    if (tid == 0) {
        float s = 0.f;
#pragma unroll
        for (int k = 0; k < 8; ++k) s += wC[k];
        symErr[t0] += s;
    }
    float zsnorm = 0.f;
#pragma unroll
    for (int k = 0; k < 8; ++k) zsnorm += wD[k];
    {
        int c = tid & 63, sl = tid >> 6;
        float pd = 0.f, pc = 0.f;
        int kk0 = sl * 128;
#pragma unroll 4
        for (int k = kk0; k < kk0 + 128; ++k) {
            float wv = conT[(size_t)k * NCON + c];
            pd += wv * s_z[k];
            pc += wv * wv;
        }
        s_pd[tid] = pd; s_pc[tid] = pc;
    }
    __syncthreads();
    if (tid < 64) {
        float dot2 = 0.f, cn2 = 0.f;
#pragma unroll
        for (int i = 0; i < 8; ++i) { dot2 += s_pd[tid + 64 * i]; cn2 += s_pc[tid + 64 * i]; }
        float dc = (zsnorm + cn2) - 2.f * dot2;
        int ic = tid;
        wave_argmin(dc, ic);
        if (tid == 0) s_ci[0] = ic;
    }
    __syncthreads();
    int ci0 = s_ci[0];
    {
        const float* crow = con + (size_t)ci0 * D2;
        float p = 0.f;
#pragma unroll
        for (int r = 0; r < 2; ++r) {
            int e = r * 512 + tid;
            float diff = crow[e] - s_z[e];
            p += diff * diff;
        }
        p = wave_sum(p);
        if (lane == 0) wE[w] = p;
    }
    __syncthreads();
    if (tid == 0) {
        float s = 0.f;
#pragma unroll
        for (int k = 0; k < 8; ++k) s += wE[k];
        conErr[t0] += s;
    }

    // ---- fused tail: zmid row-copy + KV slot gather + bias ----
    {
        const float* zm = ZMID + (size_t)si * D2;
        zmid[(size_t)t0 * D2 + tid]       = zm[tid];
        zmid[(size_t)t0 * D2 + 512 + tid] = zm[512 + tid];
        if (doKV) {
            const float* skr = SKV + (size_t)si * 1536;
#pragma unroll
            for (int it = 0; it < 3; ++it) {
                int e = it * 512 + tid;
                float v = skr[e];
                if (e < DD) Kslot[(size_t)t0 * DD + e]        = v + kb[e];
                else        Vslot[(size_t)t0 * D2 + (e - DD)] = v + vb[e - DD];
            }
        }
    }
}

// ---------------- dec combine: rows = sum of 16 partials + dec_b ----------------
__global__ void deccomb_kernel(const float* __restrict__ P, const float* __restrict__ db,
                               float* __restrict__ rows) {
    int t = blockIdx.x, j = threadIdx.x;
    float v = 0.f;
#pragma unroll
    for (int s = 0; s < 16; ++s)
        v += P[((size_t)s * NTOK + t) * VOCAB + j];
    rows[(size_t)t * VOCAB + j] = v + db[j];
}

// ---------------- scatter + in-block hist + loss (last block) ----------------
__global__ __launch_bounds__(256) void scatterloss_kernel(const int* __restrict__ x,
                                                          const float* __restrict__ rows,
                                                          float* __restrict__ out,
                                                          const float* __restrict__ symErr,
                                                          const float* __restrict__ conErr) {
    int tid = threadIdx.x;
    if (blockIdx.x == BS_TOT / 4) {
        __shared__ int h[256];
        __shared__ double rs[256], rc[256];
        h[tid] = 0;
        __syncthreads();
        for (int i = tid; i < BS_TOT; i += 256) atomicAdd(&h[x[i]], 1);
        __syncthreads();
        rs[tid] = (double)h[tid] * (double)symErr[tid];
        rc[tid] = (double)h[tid] * (double)conErr[tid];
        __syncthreads();
        for (int off = 128; off > 0; off >>= 1) {
            if (tid < off) { rs[tid] += rs[tid + off]; rc[tid] += rc[tid + off]; }
            __syncthreads();
        }
        if (tid == 0) {
            const double denom = (double)BS_TOT * (double)D2;
            out[(size_t)BS_TOT * VOCAB]     = (float)(1.25 * rs[0] / denom);
            out[(size_t)BS_TOT * VOCAB + 1] = (float)(1.25 * rc[0] / denom);
        }
        return;
    }
    int pos = blockIdx.x * 4 + (tid >> 6);
    int lane = tid & 63;
    int v = x[pos];
    const float4* r = (const float4*)(rows + (size_t)v * VOCAB);
    ((float4*)(out + (size_t)pos * VOCAB))[lane] = r[lane];
}

// ---------------- fused setup: 6 transposes + zero + buildcw + embed + symnorm ----------
// grid 3905, block 512 flat.
__global__ __launch_bounds__(512) void setup_kernel(const float* __restrict__ qw,
                                                    const float* __restrict__ kw,
                                                    const float* __restrict__ vw,
                                                    const float* __restrict__ sym,
                                                    const float* __restrict__ dec_w,
                                                    const float* __restrict__ con,
                                                    const float* __restrict__ Wr,
                                                    const float* __restrict__ Wi,
                                                    const float* __restrict__ mag,
                                                    const float* __restrict__ phase,
                                                    float* __restrict__ qwT,
                                                    float* __restrict__ KVT,
                                                    float* __restrict__ symT,
                                                    float* __restrict__ decT,
                                                    float* __restrict__ conT,
                                                    float* __restrict__ CW,
                                                    float* __restrict__ dst,
                                                    float* __restrict__ snorm,
                                                    float* __restrict__ symErr,
                                                    float* __restrict__ conErr) {
    __shared__ float t[32][33];
    __shared__ float tr[32][33], ti[32][33];
    __shared__ float s_w[8];
    int b = blockIdx.x;
    int tid = threadIdx.x;

    if (b < 2880) {   // transposes (all sources have 1024 columns)
        const float* in; float* outp; int ldo;
        if      (b < 512)  {           in = qw;    outp = qwT;      ldo = DD;    }
        else if (b < 1024) { b -= 512; in = kw;    outp = KVT;      ldo = 1536;  }
        else if (b < 2048) { b -= 1024; in = vw;   outp = KVT + DD; ldo = 1536;  }
        else if (b < 2560) { b -= 2048; in = sym;  outp = symT;     ldo = NSYM;  }
        else if (b < 2816) { b -= 2560; in = dec_w; outp = decT;    ldo = VOCAB; }
        else               { b -= 2816; in = con;  outp = conT;     ldo = NCON;  }
        int bx = b & 31, by = b >> 5;
        int c0 = bx * 32, r0 = by * 32;
        int xx = tid & 31, yy = tid >> 5;   // yy in 0..15
#pragma unroll
        for (int i = 0; i < 32; i += 16)
            t[yy + i][xx] = in[(size_t)(r0 + yy + i) * D2 + c0 + xx];
        __syncthreads();
#pragma unroll
        for (int i = 0; i < 32; i += 16)
            outp[(size_t)(c0 + yy + i) * ldo + r0 + xx] = t[xx][yy + i];
        return;
    }
    if (b == 2880) {
        if (tid < 256) { symErr[tid] = 0.f; conErr[tid] = 0.f; }
        return;
    }
    if (b < 3137) {   // buildcw, 256 blocks
        int q = b - 2881;
        int j0 = (q & 15) * 32, k0 = (q >> 4) * 32;
        int xx = tid & 31, yy = tid >> 5;
#pragma unroll
        for (int i = 0; i < 32; i += 16) {
            tr[yy + i][xx] = Wr[(size_t)(j0 + yy + i) * DD + k0 + xx];
            ti[yy + i][xx] = Wi[(size_t)(j0 + yy + i) * DD + k0 + xx];
        }
        __syncthreads();
#pragma unroll
        for (int i = 0; i < 32; i += 16) {
            float vr = tr[xx][yy + i];
            float vi = ti[xx][yy + i];
            int k = k0 + yy + i, j = j0 + xx;
            CW[(size_t)k * D2 + j]             = vr;
            CW[(size_t)k * D2 + DD + j]        = vi;
            CW[(size_t)(DD + k) * D2 + j]      = -vi;
            CW[(size_t)(DD + k) * D2 + DD + j] = vr;
        }
        return;
    }
    if (b < 3393) {   // embed, 256 blocks, 512 threads = 512 j
        int v = b - 3137, j = tid;
        float r = mag[v * DD + j], th = phase[v * DD + j];
        dst[(size_t)v * D2 + j]      = r * cosf(th);
        dst[(size_t)v * D2 + DD + j] = r * sinf(th);
        return;
    }
    {   // symnorm, 512 blocks
        int c = b - 3393;
        float2 vv = ((const float2*)(sym + (size_t)c * D2))[tid];
        float p = vv.x * vv.x + vv.y * vv.y;
        p = wave_sum(p);
        int lane = tid & 63, w = tid >> 6;
        if (lane == 0) s_w[w] = p;
        __syncthreads();
        if (tid == 0) {
            float s = 0.f;
#pragma unroll
            for (int k = 0; k < 8; ++k) s += s_w[k];
            snorm[c] = s;
        }
    }
}

// ---------------- host ----------------
extern "C" void kernel_launch(void* const* d_in, const int* in_sizes, int n_in,
                              void* d_out, int out_size, void* d_ws, size_t ws_size,
                              hipStream_t stream) {
    const int*   x     = (const int*)  d_in[0];
    const float* mag   = (const float*)d_in[1];
    const float* phase = (const float*)d_in[2];
    const float* Wr    = (const float*)d_in[3];
    const float* Wi    = (const float*)d_in[4];
    const float* qw    = (const float*)d_in[5];
    const float* qb    = (const float*)d_in[6];
    const float* kw    = (const float*)d_in[7];
    const float* kb    = (const float*)d_in[8];
    const float* vw    = (const float*)d_in[9];
    const float* vb    = (const float*)d_in[10];
    const float* dec_w = (const float*)d_in[11];
    const float* dec_b = (const float*)d_in[12];
    const float* sym   = (const float*)d_in[13];
    const float* con   = (const float*)d_in[14];
    float* out = (float*)d_out;

    // workspace layout (floats)
    float* ws     = (float*)d_ws;
    float* bufA   = ws;                          // 262144
    float* bufB   = bufA + NTOK * D2;            // 262144
    float* Kmem   = bufB + NTOK * D2;            // 786432
    float* Vmem   = Kmem + NDEPTH * NTOK * DD;   // 1572864
    float* rows   = Vmem + NDEPTH * NTOK * D2;   // 65536
    float* CW     = rows + NTOK * VOCAB;         // 1048576
    float* qwT    = CW + D2 * D2;                // 524288
    float* KVT    = qwT + D2 * DD;               // 1572864
    float* symT   = KVT + D2 * 1536;             // 524288
    float* decT   = symT + D2 * NSYM;            // 262144
    float* conT   = decT + D2 * VOCAB;           // 65536
    float* bigP   = conT + D2 * NCON;            // 2097152
    float* ZMID   = bigP + 8 * NTOK * D2;        // 524288  (old SC slot)
    float* SKV    = ZMID + NSYM * D2;            // 786432
    float* snorm  = bigP + 8 * NTOK * D2 + 4 * NTOK * 1536;  // 512
    float* conf   = snorm + NSYM;                // 256
    float* symErr = conf + NTOK;                 // 256
    float* conErr = symErr + NTOK;               // 256
    int*   si     = (int*)(conErr + NTOK);       // 256 (old hist slot)

    float* symP = bigP + 1048576;       // 8*256*512
    float* decP = bigP;                 // 16*256*256
    float* ZQP  = bigP;                 // 4*512*512 = 1048576 (free during depths;
                                        //   clobbered only by look cells, after last attend)

    // precomp scratch (live only between precomp2 and precombine2):
    float* SCP  = bigP;                 // 4*512*1024 = 2097152 (== bigP size)
    float* SKVP = Vmem;                 // 2*512*1536 = 1572864 (Vmem first written later)

    setup_kernel<<<3905, 512, 0, stream>>>(qw, kw, vw, sym, dec_w, con, Wr, Wi, mag, phase,
                                           qwT, KVT, symT, decT, conT, CW,
                                           bufA, snorm, symErr, conErr);
    precomp2_kernel<<<896, 256, 0, stream>>>(CW, KVT, sym, SCP, SKVP);
    precombine2_kernel<<<1024, 256, 0, stream>>>(SCP, SKVP, ZMID, SKV);

    // ---------- d = 0: cell GEMM (embed input) -> epi -> sym+ZQ -> finishG2 ----------
    gemmT_kernel<128><<<dim3(16, 4, 8), 256, 0, stream>>>(CW, bufA, bigP, D2);
    epi_kernel<<<dim3(2, 256), 256, 0, stream>>>(bigP, bufB);
    symzq_kernel<<<512, 256, 0, stream>>>(symT, bufB, symP, qwT, ZMID, ZQP);
    finishG2_kernel<<<NTOK, 512, 0, stream>>>(bufB, sym, snorm, con, conT, symP,
                                              conf, symErr, conErr,
                                              ZMID, SKV, bufA, kb, vb,
                                              Kmem, Vmem, si, 1);
    float* cur = bufA;   // z_mid for depth 1
    float* oth = bufB;

    // ---------- d = 1..5: attendZ -> symgemm -> finishG2 ----------
    for (int d = 1; d < NDEPTH; ++d) {
        attendZ_kernel<<<NTOK, 256, 0, stream>>>(cur, ZQP, qb, Kmem, Vmem, conf, si, d);
        gemmT_kernel<128><<<dim3(8, 4, 8), 256, 0, stream>>>(symT, cur, symP, NSYM);
        finishG2_kernel<<<NTOK, 512, 0, stream>>>(cur, sym, snorm, con, conT, symP,
                                                  conf, symErr, conErr,
                                                  ZMID, SKV, oth, kb, vb,
                                                  Kmem + (size_t)d * NTOK * DD,
                                                  Vmem + (size_t)d * NTOK * D2,
                                                  si, d < NDEPTH - 1 ? 1 : 0);
        { float* t = cur; cur = oth; oth = t; }
    }

    // cur = z after look-1 cell (zmid from depth-5 finishG2). Two more look cells:
    for (int l = 1; l < NLOOK; ++l) {
        gemmT_kernel<128><<<dim3(16, 4, 8), 256, 0, stream>>>(CW, cur, bigP, D2);
        epi_kernel<<<dim3(2, 256), 256, 0, stream>>>(bigP, oth);
        { float* t = cur; cur = oth; oth = t; }
    }

    // ---------- decode ----------
    gemmT_kernel<64><<<dim3(4, 4, 16), 256, 0, stream>>>(decT, cur, decP, VOCAB);
    deccomb_kernel<<<256, 256, 0, stream>>>(decP, dec_b, rows);
    scatterloss_kernel<<<BS_TOT / 4 + 1, 256, 0, stream>>>(x, rows, out, symErr, conErr);
}